// Round 11
// baseline (181.542 us; speedup 1.0000x reference)
//
#include <hip/hip_runtime.h>
#include <hip/hip_bf16.h>
#include <math.h>

#define N_ 8192
#define A_ 512
#define D_ 512
#define NN_ 3
#define KPARTS 4

// ---------------------------------------------------------------------------
// Fast exact-GELU: erf via Abramowitz-Stegun 7.1.26 (|err| <= 1.5e-7).
// ---------------------------------------------------------------------------
__device__ __forceinline__ float gelu_erf_fast(float x) {
  const float z  = fabsf(x) * 0.70710678118654752440f;
  const float t  = __builtin_amdgcn_rcpf(fmaf(0.3275911f, z, 1.0f));
  float p = fmaf(1.061405429f, t, -1.453152027f);
  p = fmaf(p, t, 1.421413741f);
  p = fmaf(p, t, -0.284496736f);
  p = fmaf(p, t, 0.254829592f);
  p = p * t;
  const float e  = exp2f(z * z * -1.44269504088896340736f);
  float erfz = fmaf(-p, e, 1.0f);
  erfz = copysignf(erfz, x);
  return 0.5f * x * (1.0f + erfz);
}

// ---------------------------------------------------------------------------
// Kernel 0: sq[i] = ||a_i||^2. (unchanged)
// ---------------------------------------------------------------------------
__global__ __launch_bounds__(64) void sq_kernel(
    const float* __restrict__ anchors, float* __restrict__ sq) {
  const int i = blockIdx.x;
  const int l = threadIdx.x;
  const float4* a = reinterpret_cast<const float4*>(anchors + (size_t)i * D_);
  float s = 0.f;
  for (int k = l; k < D_ / 4; k += 64) {
    float4 v = a[k];
    s += v.x * v.x + v.y * v.y + v.z * v.z + v.w * v.w;
  }
#pragma unroll
  for (int d = 32; d > 0; d >>= 1) s += __shfl_down(s, d);
  if (l == 0) sq[i] = s;
}

// ---------------------------------------------------------------------------
// Kernel 1: G_z = partial gram over K-part z. (unchanged)
// ---------------------------------------------------------------------------
__global__ __launch_bounds__(256) void gram_tiled_kernel(
    const float* __restrict__ anchors, float* __restrict__ G) {
  __shared__ float At[32][68];
  __shared__ float Bt[32][68];

  const int tx = threadIdx.x;
  const int ty = threadIdx.y;
  const int tid = ty * 16 + tx;
  const int i0 = blockIdx.y * 64;
  const int j0 = blockIdx.x * 64;
  const int z  = blockIdx.z;
  float* Gz = G + (size_t)z * A_ * A_;

  const int r0 = tid >> 3;
  const int c4 = tid & 7;

  float acc[4][4];
#pragma unroll
  for (int m = 0; m < 4; ++m)
#pragma unroll
    for (int n = 0; n < 4; ++n) acc[m][n] = 0.f;

  for (int kt = z * (16 / KPARTS); kt < (z + 1) * (16 / KPARTS); ++kt) {
    const int kb = kt * 32 + c4 * 4;
    float4 va = *reinterpret_cast<const float4*>(&anchors[(size_t)(i0 + r0) * D_ + kb]);
    float4 vb = *reinterpret_cast<const float4*>(&anchors[(size_t)(i0 + r0 + 32) * D_ + kb]);
    float4 wa = *reinterpret_cast<const float4*>(&anchors[(size_t)(j0 + r0) * D_ + kb]);
    float4 wb = *reinterpret_cast<const float4*>(&anchors[(size_t)(j0 + r0 + 32) * D_ + kb]);
    __syncthreads();
    const int kc = c4 * 4;
    At[kc + 0][r0] = va.x; At[kc + 1][r0] = va.y; At[kc + 2][r0] = va.z; At[kc + 3][r0] = va.w;
    At[kc + 0][r0 + 32] = vb.x; At[kc + 1][r0 + 32] = vb.y; At[kc + 2][r0 + 32] = vb.z; At[kc + 3][r0 + 32] = vb.w;
    Bt[kc + 0][r0] = wa.x; Bt[kc + 1][r0] = wa.y; Bt[kc + 2][r0] = wa.z; Bt[kc + 3][r0] = wa.w;
    Bt[kc + 0][r0 + 32] = wb.x; Bt[kc + 1][r0 + 32] = wb.y; Bt[kc + 2][r0 + 32] = wb.z; Bt[kc + 3][r0 + 32] = wb.w;
    __syncthreads();

#pragma unroll
    for (int kk = 0; kk < 32; ++kk) {
      float4 a = *reinterpret_cast<const float4*>(&At[kk][ty * 4]);
      float4 b = *reinterpret_cast<const float4*>(&Bt[kk][tx * 4]);
      acc[0][0] += a.x * b.x; acc[0][1] += a.x * b.y; acc[0][2] += a.x * b.z; acc[0][3] += a.x * b.w;
      acc[1][0] += a.y * b.x; acc[1][1] += a.y * b.y; acc[1][2] += a.y * b.z; acc[1][3] += a.y * b.w;
      acc[2][0] += a.z * b.x; acc[2][1] += a.z * b.y; acc[2][2] += a.z * b.z; acc[2][3] += a.z * b.w;
      acc[3][0] += a.w * b.x; acc[3][1] += a.w * b.y; acc[3][2] += a.w * b.z; acc[3][3] += a.w * b.w;
    }
  }

#pragma unroll
  for (int m = 0; m < 4; ++m) {
    float4 st;
    st.x = acc[m][0]; st.y = acc[m][1]; st.z = acc[m][2]; st.w = acc[m][3];
    *reinterpret_cast<float4*>(&Gz[(size_t)(i0 + ty * 4 + m) * A_ + j0 + tx * 4]) = st;
  }
}

// ---------------------------------------------------------------------------
// Kernel 2: per-anchor 3-NN + Cayley-Menger det. (unchanged)
// ---------------------------------------------------------------------------
__device__ __forceinline__ void lexmin(float& v, int& j, float ov, int oj) {
  if (ov < v || (ov == v && oj < j)) { v = ov; j = oj; }
}

__global__ __launch_bounds__(64) void nn_det_kernel(
    const float* __restrict__ G, const float* __restrict__ sq,
    float* __restrict__ quality) {
  __shared__ float d2s[16];
  const int i = blockIdx.x;
  const int l = threadIdx.x;
  const float sqi = sq[i];
  const int jb = l * 8;

  float gg[8] = {0.f, 0.f, 0.f, 0.f, 0.f, 0.f, 0.f, 0.f};
#pragma unroll
  for (int z = 0; z < KPARTS; ++z) {
    const float* Grow = G + (size_t)z * A_ * A_ + (size_t)i * A_;
    float4 g0 = *reinterpret_cast<const float4*>(&Grow[jb]);
    float4 g1 = *reinterpret_cast<const float4*>(&Grow[jb + 4]);
    gg[0] += g0.x; gg[1] += g0.y; gg[2] += g0.z; gg[3] += g0.w;
    gg[4] += g1.x; gg[5] += g1.y; gg[6] += g1.z; gg[7] += g1.w;
  }
  float4 s0 = *reinterpret_cast<const float4*>(&sq[jb]);
  float4 s1 = *reinterpret_cast<const float4*>(&sq[jb + 4]);
  float ss[8] = { s0.x, s0.y, s0.z, s0.w, s1.x, s1.y, s1.z, s1.w };

  float dist[8];
#pragma unroll
  for (int q = 0; q < 8; ++q) {
    float d2 = fmaxf(sqi + ss[q] - 2.f * gg[q], 0.f);
    float dd = sqrtf(d2);
    if (jb + q == i) dd += 1e12f;
    dist[q] = dd;
  }

  int nn[NN_];
#pragma unroll
  for (int r = 0; r < NN_; ++r) {
    float bv = 1e30f;
    int bi = 0x7fffffff;
#pragma unroll
    for (int q = 0; q < 8; ++q) lexmin(bv, bi, dist[q], jb + q);
#pragma unroll
    for (int d = 1; d < 64; d <<= 1) {
      float ov = __shfl_xor(bv, d);
      int oi = __shfl_xor(bi, d);
      lexmin(bv, bi, ov, oi);
    }
    nn[r] = bi;
#pragma unroll
    for (int q = 0; q < 8; ++q)
      if (jb + q == bi) dist[q] = 1e30f;
  }

  if (l < 16) {
    const int p = l >> 2, q = l & 3;
    const int pi = (p == 0) ? i : ((p == 1) ? nn[0] : ((p == 2) ? nn[1] : nn[2]));
    const int qi = (q == 0) ? i : ((q == 1) ? nn[0] : ((q == 2) ? nn[1] : nn[2]));
    float d2f;
    if (p == q) {
      d2f = 0.f;
    } else {
      float g = 0.f;
#pragma unroll
      for (int z = 0; z < KPARTS; ++z)
        g += G[(size_t)z * A_ * A_ + (size_t)pi * A_ + qi];
      d2f = sq[pi] + sq[qi] - 2.f * g;
    }
    d2s[l] = d2f;
  }
  __syncthreads();

  if (l == 0) {
    double M[5][5];
    M[0][0] = 0.0;
    for (int q = 1; q < 5; ++q) { M[0][q] = 1.0; M[q][0] = 1.0; }
    for (int p = 0; p < 4; ++p)
      for (int q = 0; q < 4; ++q)
        M[p + 1][q + 1] = (double)d2s[p * 4 + q];

    double det = 1.0;
    for (int c = 0; c < 5; ++c) {
      int piv = c;
      double mx = fabs(M[c][c]);
      for (int r2 = c + 1; r2 < 5; ++r2) {
        double v = fabs(M[r2][c]);
        if (v > mx) { mx = v; piv = r2; }
      }
      if (piv != c) {
        for (int c2 = 0; c2 < 5; ++c2) { double tmp = M[c][c2]; M[c][c2] = M[piv][c2]; M[piv][c2] = tmp; }
        det = -det;
      }
      double pv = M[c][c];
      det *= pv;
      if (pv == 0.0) break;
      for (int r2 = c + 1; r2 < 5; ++r2) {
        double f = M[r2][c] / pv;
        for (int c2 = c; c2 < 5; ++c2) M[r2][c2] -= f * M[c][c2];
      }
    }
    float raw = (float)det;
    float sg = (raw > 0.f) ? 1.f : ((raw < 0.f) ? -1.f : 0.f);
    quality[i] = sg * logf(fabsf(raw) + 1e-12f);
  }
}

// ---------------------------------------------------------------------------
// Kernel 3: normalize quality. (unchanged)
// ---------------------------------------------------------------------------
__global__ __launch_bounds__(A_) void norm_cm_kernel(
    const float* __restrict__ quality, float* __restrict__ cmn) {
  __shared__ float red[A_];
  const int t = threadIdx.x;
  float q = quality[t];
  red[t] = q;
  __syncthreads();
  for (int s = A_ / 2; s > 0; s >>= 1) {
    if (t < s) red[t] += red[t + s];
    __syncthreads();
  }
  float mean = red[0] * (1.0f / A_);
  __syncthreads();
  float dq = q - mean;
  red[t] = dq * dq;
  __syncthreads();
  for (int s = A_ / 2; s > 0; s >>= 1) {
    if (t < s) red[t] += red[t + s];
    __syncthreads();
  }
  float sd = sqrtf(red[0] * (1.0f / (A_ - 1)));
  sd = fmaxf(sd, 1e-8f);
  cmn[t] = dq / sd;
}

// ---------------------------------------------------------------------------
// PHASE ABLATION of the round-5 rank pipeline (best known, 56 µs).
// P=0 load+key+bucket; P>=1 +hist atomics; P>=2 +scan; P>=3 +scatter;
// P>=4 +probe. Dummy accumulator reads LDS back after each phase and is
// stored -> no phase can be DCE'd (rule #17). No MLP (round-8: MLP is free).
// ---------------------------------------------------------------------------
template <int P>
__global__ __launch_bounds__(A_) void rank_ab(
    const float* __restrict__ tri, float* __restrict__ dumout) {
  __shared__ int hist[256];
  __shared__ int pref[256];
  __shared__ int cursor[256];
  __shared__ unsigned long long sorted[A_];

  const int n = blockIdx.x;
  const int t = threadIdx.x;

  const float ti = tri[(size_t)n * A_ + t];
  const unsigned long long key =
      ((unsigned long long)__float_as_uint(ti) << 9) | (unsigned)t;
  int b = (int)(ti * 128.0f);
  b = (b < 0) ? 0 : ((b > 255) ? 255 : b);

  int dummy = (int)(key & 0xffff) + b;

  if constexpr (P >= 1) {
    if (t < 256) { hist[t] = 0; cursor[t] = 0; }
    __syncthreads();
    atomicAdd(&hist[b], 1);
    __syncthreads();
    dummy += hist[(t + 1) & 255];          // keep histogram live
  }

  if constexpr (P >= 2) {
    if (t < 64) {
      const int b4 = t * 4;
      int h0 = hist[b4 + 0], h1 = hist[b4 + 1], h2 = hist[b4 + 2], h3 = hist[b4 + 3];
      int s = h0 + h1 + h2 + h3;
      int incl = s;
#pragma unroll
      for (int d = 1; d < 64; d <<= 1) {
        int u = __shfl_up(incl, d);
        if (t >= d) incl += u;
      }
      int ex = incl - s;
      pref[b4 + 0] = ex;
      pref[b4 + 1] = ex + h0;
      pref[b4 + 2] = ex + h0 + h1;
      pref[b4 + 3] = ex + h0 + h1 + h2;
    }
    __syncthreads();
    dummy += pref[b];                      // keep scan live
  }

  if constexpr (P >= 3) {
    const int pos = pref[b] + atomicAdd(&cursor[b], 1);
    sorted[pos] = key;
    __syncthreads();
    dummy += (int)sorted[(t * 7) & (A_ - 1)];   // keep scatter live
  }

  if constexpr (P >= 4) {
    const int start = pref[b];
    const int len = hist[b];
    int cnt = start;
    for (int m = 0; m < len; ++m) cnt += (sorted[start + m] < key);
    dummy += cnt;
  }

  dumout[(size_t)n * A_ + t] = (float)dummy;
}

// ---------------------------------------------------------------------------
// Full gate, template'd probe: PAIR=0 round-5 len-loop (validated output);
// PAIR=1 paired probe, 2 reads/iter (fix candidate, scratch output).
// ---------------------------------------------------------------------------
template <int PAIR>
__global__ __launch_bounds__(A_) void gate_full(
    const float* __restrict__ tri, const float* __restrict__ cmn,
    const float* __restrict__ W1, const float* __restrict__ b1,
    const float* __restrict__ W2, const float* __restrict__ b2,
    float* __restrict__ out) {
  __shared__ int hist[256];
  __shared__ int pref[256];
  __shared__ int cursor[256];
  __shared__ unsigned long long sorted[A_ + 2];   // +2 pad for paired read

  const int n = blockIdx.x;
  const int t = threadIdx.x;

  const float ti = tri[(size_t)n * A_ + t];
  const unsigned long long key =
      ((unsigned long long)__float_as_uint(ti) << 9) | (unsigned)t;
  int b = (int)(ti * 128.0f);
  b = (b < 0) ? 0 : ((b > 255) ? 255 : b);

  if (t < 256) { hist[t] = 0; cursor[t] = 0; }
  __syncthreads();
  atomicAdd(&hist[b], 1);
  __syncthreads();

  if (t < 64) {
    const int b4 = t * 4;
    int h0 = hist[b4 + 0], h1 = hist[b4 + 1], h2 = hist[b4 + 2], h3 = hist[b4 + 3];
    int s = h0 + h1 + h2 + h3;
    int incl = s;
#pragma unroll
    for (int d = 1; d < 64; d <<= 1) {
      int u = __shfl_up(incl, d);
      if (t >= d) incl += u;
    }
    int ex = incl - s;
    pref[b4 + 0] = ex;
    pref[b4 + 1] = ex + h0;
    pref[b4 + 2] = ex + h0 + h1;
    pref[b4 + 3] = ex + h0 + h1 + h2;
  }
  __syncthreads();

  const int pos = pref[b] + atomicAdd(&cursor[b], 1);
  sorted[pos] = key;
  __syncthreads();

  const int start = pref[b];
  const int len = hist[b];
  int cnt = start;
  if constexpr (PAIR) {
    for (int m = 0; m < len; m += 2) {
      const unsigned long long v0 = sorted[start + m];
      const unsigned long long v1 = sorted[start + m + 1];   // padded; guarded below
      cnt += (v0 < key);
      cnt += ((m + 1 < len) && (v1 < key));
    }
  } else {
    for (int m = 0; m < len; ++m) cnt += (sorted[start + m] < key);
  }
  const float rank = (float)cnt * (1.0f / (A_ - 1));

  const float f0 = cmn[t];
  const float f1 = 1.0f - ti;

  float logit = b2[0];
#pragma unroll
  for (int k = 0; k < 16; ++k) {
    float x = fmaf(W1[k * 3 + 0], f0,
              fmaf(W1[k * 3 + 1], f1,
              fmaf(W1[k * 3 + 2], rank, b1[k])));
    logit = fmaf(W2[k], gelu_erf_fast(x), logit);
  }
  const float eneg = exp2f(logit * -1.44269504088896340736f);
  out[(size_t)n * A_ + t] = __builtin_amdgcn_rcpf(1.0f + eneg);
}

// ---------------------------------------------------------------------------
extern "C" void kernel_launch(void* const* d_in, const int* in_sizes, int n_in,
                              void* d_out, int out_size, void* d_ws, size_t ws_size,
                              hipStream_t stream) {
  // inputs: 0 embedding (unused), 1 anchors, 2 tri, 3 W1, 4 b1, 5 W2, 6 b2
  const float* anchors = (const float*)d_in[1];
  const float* tri     = (const float*)d_in[2];
  const float* W1      = (const float*)d_in[3];
  const float* b1      = (const float*)d_in[4];
  const float* W2      = (const float*)d_in[5];
  const float* b2      = (const float*)d_in[6];
  float* out = (float*)d_out;

  float* G       = (float*)d_ws;                       // KPARTS*A_*A_ (4 MB)
  float* sq      = G + (size_t)KPARTS * A_ * A_;       // A_
  float* quality = sq + A_;                            // A_
  float* cmn     = quality + A_;                       // A_
  float* abl     = cmn + A_;                           // N_*A_ scratch (16 MB)

  sq_kernel<<<A_, 64, 0, stream>>>(anchors, sq);
  gram_tiled_kernel<<<dim3(8, 8, KPARTS), dim3(16, 16), 0, stream>>>(anchors, G);
  nn_det_kernel<<<A_, 64, 0, stream>>>(G, sq, quality);
  norm_cm_kernel<<<1, A_, 0, stream>>>(quality, cmn);

  // --- phase ablation (scratch output; read dur_us per dispatch) ---
  rank_ab<0><<<N_, A_, 0, stream>>>(tri, abl);   // load+key+bucket
  rank_ab<1><<<N_, A_, 0, stream>>>(tri, abl);   // +hist atomics
  rank_ab<2><<<N_, A_, 0, stream>>>(tri, abl);   // +scan
  rank_ab<3><<<N_, A_, 0, stream>>>(tri, abl);   // +scatter
  rank_ab<4><<<N_, A_, 0, stream>>>(tri, abl);   // +probe (== V1)
  gate_full<1><<<N_, A_, 0, stream>>>(tri, cmn, W1, b1, W2, b2, abl);  // paired-probe fix candidate
  // --- validated output (round-5 proven path) ---
  gate_full<0><<<N_, A_, 0, stream>>>(tri, cmn, W1, b1, W2, b2, out);
}

// Round 12
// 97.926 us; speedup vs baseline: 1.8539x; 1.8539x over previous
//
#include <hip/hip_runtime.h>
#include <hip/hip_bf16.h>
#include <math.h>

#define N_ 8192
#define A_ 512
#define D_ 512
#define NN_ 3
#define KPARTS 4

// ---------------------------------------------------------------------------
// Fast exact-GELU: erf via Abramowitz-Stegun 7.1.26 (|err| <= 1.5e-7).
// ---------------------------------------------------------------------------
__device__ __forceinline__ float gelu_erf_fast(float x) {
  const float z  = fabsf(x) * 0.70710678118654752440f;
  const float t  = __builtin_amdgcn_rcpf(fmaf(0.3275911f, z, 1.0f));
  float p = fmaf(1.061405429f, t, -1.453152027f);
  p = fmaf(p, t, 1.421413741f);
  p = fmaf(p, t, -0.284496736f);
  p = fmaf(p, t, 0.254829592f);
  p = p * t;
  const float e  = exp2f(z * z * -1.44269504088896340736f);
  float erfz = fmaf(-p, e, 1.0f);
  erfz = copysignf(erfz, x);
  return 0.5f * x * (1.0f + erfz);
}

// ---------------------------------------------------------------------------
// Kernel 0: sq[i] = ||a_i||^2. (unchanged)
// ---------------------------------------------------------------------------
__global__ __launch_bounds__(64) void sq_kernel(
    const float* __restrict__ anchors, float* __restrict__ sq) {
  const int i = blockIdx.x;
  const int l = threadIdx.x;
  const float4* a = reinterpret_cast<const float4*>(anchors + (size_t)i * D_);
  float s = 0.f;
  for (int k = l; k < D_ / 4; k += 64) {
    float4 v = a[k];
    s += v.x * v.x + v.y * v.y + v.z * v.z + v.w * v.w;
  }
#pragma unroll
  for (int d = 32; d > 0; d >>= 1) s += __shfl_down(s, d);
  if (l == 0) sq[i] = s;
}

// ---------------------------------------------------------------------------
// Kernel 1: G_z = partial gram over K-part z. (unchanged)
// ---------------------------------------------------------------------------
__global__ __launch_bounds__(256) void gram_tiled_kernel(
    const float* __restrict__ anchors, float* __restrict__ G) {
  __shared__ float At[32][68];
  __shared__ float Bt[32][68];

  const int tx = threadIdx.x;
  const int ty = threadIdx.y;
  const int tid = ty * 16 + tx;
  const int i0 = blockIdx.y * 64;
  const int j0 = blockIdx.x * 64;
  const int z  = blockIdx.z;
  float* Gz = G + (size_t)z * A_ * A_;

  const int r0 = tid >> 3;
  const int c4 = tid & 7;

  float acc[4][4];
#pragma unroll
  for (int m = 0; m < 4; ++m)
#pragma unroll
    for (int n = 0; n < 4; ++n) acc[m][n] = 0.f;

  for (int kt = z * (16 / KPARTS); kt < (z + 1) * (16 / KPARTS); ++kt) {
    const int kb = kt * 32 + c4 * 4;
    float4 va = *reinterpret_cast<const float4*>(&anchors[(size_t)(i0 + r0) * D_ + kb]);
    float4 vb = *reinterpret_cast<const float4*>(&anchors[(size_t)(i0 + r0 + 32) * D_ + kb]);
    float4 wa = *reinterpret_cast<const float4*>(&anchors[(size_t)(j0 + r0) * D_ + kb]);
    float4 wb = *reinterpret_cast<const float4*>(&anchors[(size_t)(j0 + r0 + 32) * D_ + kb]);
    __syncthreads();
    const int kc = c4 * 4;
    At[kc + 0][r0] = va.x; At[kc + 1][r0] = va.y; At[kc + 2][r0] = va.z; At[kc + 3][r0] = va.w;
    At[kc + 0][r0 + 32] = vb.x; At[kc + 1][r0 + 32] = vb.y; At[kc + 2][r0 + 32] = vb.z; At[kc + 3][r0 + 32] = vb.w;
    Bt[kc + 0][r0] = wa.x; Bt[kc + 1][r0] = wa.y; Bt[kc + 2][r0] = wa.z; Bt[kc + 3][r0] = wa.w;
    Bt[kc + 0][r0 + 32] = wb.x; Bt[kc + 1][r0 + 32] = wb.y; Bt[kc + 2][r0 + 32] = wb.z; Bt[kc + 3][r0 + 32] = wb.w;
    __syncthreads();

#pragma unroll
    for (int kk = 0; kk < 32; ++kk) {
      float4 a = *reinterpret_cast<const float4*>(&At[kk][ty * 4]);
      float4 b = *reinterpret_cast<const float4*>(&Bt[kk][tx * 4]);
      acc[0][0] += a.x * b.x; acc[0][1] += a.x * b.y; acc[0][2] += a.x * b.z; acc[0][3] += a.x * b.w;
      acc[1][0] += a.y * b.x; acc[1][1] += a.y * b.y; acc[1][2] += a.y * b.z; acc[1][3] += a.y * b.w;
      acc[2][0] += a.z * b.x; acc[2][1] += a.z * b.y; acc[2][2] += a.z * b.z; acc[2][3] += a.z * b.w;
      acc[3][0] += a.w * b.x; acc[3][1] += a.w * b.y; acc[3][2] += a.w * b.z; acc[3][3] += a.w * b.w;
    }
  }

#pragma unroll
  for (int m = 0; m < 4; ++m) {
    float4 st;
    st.x = acc[m][0]; st.y = acc[m][1]; st.z = acc[m][2]; st.w = acc[m][3];
    *reinterpret_cast<float4*>(&Gz[(size_t)(i0 + ty * 4 + m) * A_ + j0 + tx * 4]) = st;
  }
}

// ---------------------------------------------------------------------------
// Kernel 2: per-anchor 3-NN + Cayley-Menger det. (unchanged)
// ---------------------------------------------------------------------------
__device__ __forceinline__ void lexmin(float& v, int& j, float ov, int oj) {
  if (ov < v || (ov == v && oj < j)) { v = ov; j = oj; }
}

__global__ __launch_bounds__(64) void nn_det_kernel(
    const float* __restrict__ G, const float* __restrict__ sq,
    float* __restrict__ quality) {
  __shared__ float d2s[16];
  const int i = blockIdx.x;
  const int l = threadIdx.x;
  const float sqi = sq[i];
  const int jb = l * 8;

  float gg[8] = {0.f, 0.f, 0.f, 0.f, 0.f, 0.f, 0.f, 0.f};
#pragma unroll
  for (int z = 0; z < KPARTS; ++z) {
    const float* Grow = G + (size_t)z * A_ * A_ + (size_t)i * A_;
    float4 g0 = *reinterpret_cast<const float4*>(&Grow[jb]);
    float4 g1 = *reinterpret_cast<const float4*>(&Grow[jb + 4]);
    gg[0] += g0.x; gg[1] += g0.y; gg[2] += g0.z; gg[3] += g0.w;
    gg[4] += g1.x; gg[5] += g1.y; gg[6] += g1.z; gg[7] += g1.w;
  }
  float4 s0 = *reinterpret_cast<const float4*>(&sq[jb]);
  float4 s1 = *reinterpret_cast<const float4*>(&sq[jb + 4]);
  float ss[8] = { s0.x, s0.y, s0.z, s0.w, s1.x, s1.y, s1.z, s1.w };

  float dist[8];
#pragma unroll
  for (int q = 0; q < 8; ++q) {
    float d2 = fmaxf(sqi + ss[q] - 2.f * gg[q], 0.f);
    float dd = sqrtf(d2);
    if (jb + q == i) dd += 1e12f;
    dist[q] = dd;
  }

  int nn[NN_];
#pragma unroll
  for (int r = 0; r < NN_; ++r) {
    float bv = 1e30f;
    int bi = 0x7fffffff;
#pragma unroll
    for (int q = 0; q < 8; ++q) lexmin(bv, bi, dist[q], jb + q);
#pragma unroll
    for (int d = 1; d < 64; d <<= 1) {
      float ov = __shfl_xor(bv, d);
      int oi = __shfl_xor(bi, d);
      lexmin(bv, bi, ov, oi);
    }
    nn[r] = bi;
#pragma unroll
    for (int q = 0; q < 8; ++q)
      if (jb + q == bi) dist[q] = 1e30f;
  }

  if (l < 16) {
    const int p = l >> 2, q = l & 3;
    const int pi = (p == 0) ? i : ((p == 1) ? nn[0] : ((p == 2) ? nn[1] : nn[2]));
    const int qi = (q == 0) ? i : ((q == 1) ? nn[0] : ((q == 2) ? nn[1] : nn[2]));
    float d2f;
    if (p == q) {
      d2f = 0.f;
    } else {
      float g = 0.f;
#pragma unroll
      for (int z = 0; z < KPARTS; ++z)
        g += G[(size_t)z * A_ * A_ + (size_t)pi * A_ + qi];
      d2f = sq[pi] + sq[qi] - 2.f * g;
    }
    d2s[l] = d2f;
  }
  __syncthreads();

  if (l == 0) {
    double M[5][5];
    M[0][0] = 0.0;
    for (int q = 1; q < 5; ++q) { M[0][q] = 1.0; M[q][0] = 1.0; }
    for (int p = 0; p < 4; ++p)
      for (int q = 0; q < 4; ++q)
        M[p + 1][q + 1] = (double)d2s[p * 4 + q];

    double det = 1.0;
    for (int c = 0; c < 5; ++c) {
      int piv = c;
      double mx = fabs(M[c][c]);
      for (int r2 = c + 1; r2 < 5; ++r2) {
        double v = fabs(M[r2][c]);
        if (v > mx) { mx = v; piv = r2; }
      }
      if (piv != c) {
        for (int c2 = 0; c2 < 5; ++c2) { double tmp = M[c][c2]; M[c][c2] = M[piv][c2]; M[piv][c2] = tmp; }
        det = -det;
      }
      double pv = M[c][c];
      det *= pv;
      if (pv == 0.0) break;
      for (int r2 = c + 1; r2 < 5; ++r2) {
        double f = M[r2][c] / pv;
        for (int c2 = c; c2 < 5; ++c2) M[r2][c2] -= f * M[c][c2];
      }
    }
    float raw = (float)det;
    float sg = (raw > 0.f) ? 1.f : ((raw < 0.f) ? -1.f : 0.f);
    quality[i] = sg * logf(fabsf(raw) + 1e-12f);
  }
}

// ---------------------------------------------------------------------------
// Kernel 3: normalize quality. (unchanged)
// ---------------------------------------------------------------------------
__global__ __launch_bounds__(A_) void norm_cm_kernel(
    const float* __restrict__ quality, float* __restrict__ cmn) {
  __shared__ float red[A_];
  const int t = threadIdx.x;
  float q = quality[t];
  red[t] = q;
  __syncthreads();
  for (int s = A_ / 2; s > 0; s >>= 1) {
    if (t < s) red[t] += red[t + s];
    __syncthreads();
  }
  float mean = red[0] * (1.0f / A_);
  __syncthreads();
  float dq = q - mean;
  red[t] = dq * dq;
  __syncthreads();
  for (int s = A_ / 2; s > 0; s >>= 1) {
    if (t < s) red[t] += red[t + s];
    __syncthreads();
  }
  float sd = sqrtf(red[0] * (1.0f / (A_ - 1)));
  sd = fmaxf(sd, 1e-8f);
  cmn[t] = dq / sd;
}

// ---------------------------------------------------------------------------
// Kernel 4a: RANK ONLY (round-5 proven pipeline), store cnt as u16.
// One row per 512-thread block.
// ---------------------------------------------------------------------------
__global__ __launch_bounds__(A_) void rank_kernel(
    const float* __restrict__ tri, unsigned short* __restrict__ rankout) {
  __shared__ int hist[256];
  __shared__ int pref[256];
  __shared__ int cursor[256];
  __shared__ unsigned long long sorted[A_];

  const int n = blockIdx.x;
  const int t = threadIdx.x;

  const float ti = tri[(size_t)n * A_ + t];
  const unsigned long long key =
      ((unsigned long long)__float_as_uint(ti) << 9) | (unsigned)t;
  int b = (int)(ti * 128.0f);
  b = (b < 0) ? 0 : ((b > 255) ? 255 : b);

  if (t < 256) { hist[t] = 0; cursor[t] = 0; }
  __syncthreads();
  atomicAdd(&hist[b], 1);
  __syncthreads();

  if (t < 64) {
    const int b4 = t * 4;
    int h0 = hist[b4 + 0], h1 = hist[b4 + 1], h2 = hist[b4 + 2], h3 = hist[b4 + 3];
    int s = h0 + h1 + h2 + h3;
    int incl = s;
#pragma unroll
    for (int d = 1; d < 64; d <<= 1) {
      int u = __shfl_up(incl, d);
      if (t >= d) incl += u;
    }
    int ex = incl - s;
    pref[b4 + 0] = ex;
    pref[b4 + 1] = ex + h0;
    pref[b4 + 2] = ex + h0 + h1;
    pref[b4 + 3] = ex + h0 + h1 + h2;
  }
  __syncthreads();

  const int pos = pref[b] + atomicAdd(&cursor[b], 1);
  sorted[pos] = key;
  __syncthreads();

  const int start = pref[b];
  const int len = hist[b];
  int cnt = start;
  for (int m = 0; m < len; ++m) cnt += (sorted[start + m] < key);

  rankout[(size_t)n * A_ + t] = (unsigned short)cnt;
}

// ---------------------------------------------------------------------------
// Kernel 4b: MLP ONLY — pure streaming, no LDS/barriers. 4 elems/thread.
// ---------------------------------------------------------------------------
__global__ __launch_bounds__(256) void mlp_kernel(
    const float* __restrict__ tri, const unsigned short* __restrict__ rankin,
    const float* __restrict__ cmn,
    const float* __restrict__ W1, const float* __restrict__ b1,
    const float* __restrict__ W2, const float* __restrict__ b2,
    float* __restrict__ out) {
  const int idx4 = (blockIdx.x * 256 + threadIdx.x) * 4;

  float4 tv = *reinterpret_cast<const float4*>(tri + idx4);
  ushort4 rv = *reinterpret_cast<const ushort4*>(rankin + idx4);
  float4 cv = *reinterpret_cast<const float4*>(cmn + (idx4 & (A_ - 1)));

  const float ti[4]  = { tv.x, tv.y, tv.z, tv.w };
  const float f0[4]  = { cv.x, cv.y, cv.z, cv.w };
  const float rk[4]  = { (float)rv.x, (float)rv.y, (float)rv.z, (float)rv.w };

  float res[4];
#pragma unroll
  for (int q = 0; q < 4; ++q) {
    const float rank = rk[q] * (1.0f / (A_ - 1));
    const float f1 = 1.0f - ti[q];
    float logit = b2[0];
#pragma unroll
    for (int k = 0; k < 16; ++k) {
      float x = fmaf(W1[k * 3 + 0], f0[q],
                fmaf(W1[k * 3 + 1], f1,
                fmaf(W1[k * 3 + 2], rank, b1[k])));
      logit = fmaf(W2[k], gelu_erf_fast(x), logit);
    }
    res[q] = __builtin_amdgcn_rcpf(1.0f + exp2f(logit * -1.44269504088896340736f));
  }
  float4 ov;
  ov.x = res[0]; ov.y = res[1]; ov.z = res[2]; ov.w = res[3];
  *reinterpret_cast<float4*>(out + idx4) = ov;
}

// ---------------------------------------------------------------------------
extern "C" void kernel_launch(void* const* d_in, const int* in_sizes, int n_in,
                              void* d_out, int out_size, void* d_ws, size_t ws_size,
                              hipStream_t stream) {
  // inputs: 0 embedding (unused), 1 anchors, 2 tri, 3 W1, 4 b1, 5 W2, 6 b2
  const float* anchors = (const float*)d_in[1];
  const float* tri     = (const float*)d_in[2];
  const float* W1      = (const float*)d_in[3];
  const float* b1      = (const float*)d_in[4];
  const float* W2      = (const float*)d_in[5];
  const float* b2      = (const float*)d_in[6];
  float* out = (float*)d_out;

  float* G        = (float*)d_ws;                      // KPARTS*A_*A_ (4 MB)
  float* sq       = G + (size_t)KPARTS * A_ * A_;      // A_
  float* quality  = sq + A_;                           // A_
  float* cmn      = quality + A_;                      // A_
  unsigned short* ranks = (unsigned short*)(cmn + A_); // N_*A_ u16 (8 MB)

  sq_kernel<<<A_, 64, 0, stream>>>(anchors, sq);
  gram_tiled_kernel<<<dim3(8, 8, KPARTS), dim3(16, 16), 0, stream>>>(anchors, G);
  nn_det_kernel<<<A_, 64, 0, stream>>>(G, sq, quality);
  norm_cm_kernel<<<1, A_, 0, stream>>>(quality, cmn);
  rank_kernel<<<N_, A_, 0, stream>>>(tri, ranks);
  mlp_kernel<<<(N_ * A_) / (4 * 256), 256, 0, stream>>>(
      tri, ranks, cmn, W1, b1, W2, b2, out);
}

// Round 13
// 93.203 us; speedup vs baseline: 1.9478x; 1.0507x over previous
//
#include <hip/hip_runtime.h>
#include <hip/hip_bf16.h>
#include <math.h>

#define N_ 8192
#define A_ 512
#define D_ 512
#define NN_ 3
#define KPARTS 4

// ---------------------------------------------------------------------------
// Fast exact-GELU: erf via Abramowitz-Stegun 7.1.26 (|err| <= 1.5e-7).
// ---------------------------------------------------------------------------
__device__ __forceinline__ float gelu_erf_fast(float x) {
  const float z  = fabsf(x) * 0.70710678118654752440f;
  const float t  = __builtin_amdgcn_rcpf(fmaf(0.3275911f, z, 1.0f));
  float p = fmaf(1.061405429f, t, -1.453152027f);
  p = fmaf(p, t, 1.421413741f);
  p = fmaf(p, t, -0.284496736f);
  p = fmaf(p, t, 0.254829592f);
  p = p * t;
  const float e  = exp2f(z * z * -1.44269504088896340736f);
  float erfz = fmaf(-p, e, 1.0f);
  erfz = copysignf(erfz, x);
  return 0.5f * x * (1.0f + erfz);
}

// ---------------------------------------------------------------------------
// Kernel 0: sq[i] = ||a_i||^2. (unchanged)
// ---------------------------------------------------------------------------
__global__ __launch_bounds__(64) void sq_kernel(
    const float* __restrict__ anchors, float* __restrict__ sq) {
  const int i = blockIdx.x;
  const int l = threadIdx.x;
  const float4* a = reinterpret_cast<const float4*>(anchors + (size_t)i * D_);
  float s = 0.f;
  for (int k = l; k < D_ / 4; k += 64) {
    float4 v = a[k];
    s += v.x * v.x + v.y * v.y + v.z * v.z + v.w * v.w;
  }
#pragma unroll
  for (int d = 32; d > 0; d >>= 1) s += __shfl_down(s, d);
  if (l == 0) sq[i] = s;
}

// ---------------------------------------------------------------------------
// Kernel 1: G_z = partial gram over K-part z. (unchanged)
// ---------------------------------------------------------------------------
__global__ __launch_bounds__(256) void gram_tiled_kernel(
    const float* __restrict__ anchors, float* __restrict__ G) {
  __shared__ float At[32][68];
  __shared__ float Bt[32][68];

  const int tx = threadIdx.x;
  const int ty = threadIdx.y;
  const int tid = ty * 16 + tx;
  const int i0 = blockIdx.y * 64;
  const int j0 = blockIdx.x * 64;
  const int z  = blockIdx.z;
  float* Gz = G + (size_t)z * A_ * A_;

  const int r0 = tid >> 3;
  const int c4 = tid & 7;

  float acc[4][4];
#pragma unroll
  for (int m = 0; m < 4; ++m)
#pragma unroll
    for (int n = 0; n < 4; ++n) acc[m][n] = 0.f;

  for (int kt = z * (16 / KPARTS); kt < (z + 1) * (16 / KPARTS); ++kt) {
    const int kb = kt * 32 + c4 * 4;
    float4 va = *reinterpret_cast<const float4*>(&anchors[(size_t)(i0 + r0) * D_ + kb]);
    float4 vb = *reinterpret_cast<const float4*>(&anchors[(size_t)(i0 + r0 + 32) * D_ + kb]);
    float4 wa = *reinterpret_cast<const float4*>(&anchors[(size_t)(j0 + r0) * D_ + kb]);
    float4 wb = *reinterpret_cast<const float4*>(&anchors[(size_t)(j0 + r0 + 32) * D_ + kb]);
    __syncthreads();
    const int kc = c4 * 4;
    At[kc + 0][r0] = va.x; At[kc + 1][r0] = va.y; At[kc + 2][r0] = va.z; At[kc + 3][r0] = va.w;
    At[kc + 0][r0 + 32] = vb.x; At[kc + 1][r0 + 32] = vb.y; At[kc + 2][r0 + 32] = vb.z; At[kc + 3][r0 + 32] = vb.w;
    Bt[kc + 0][r0] = wa.x; Bt[kc + 1][r0] = wa.y; Bt[kc + 2][r0] = wa.z; Bt[kc + 3][r0] = wa.w;
    Bt[kc + 0][r0 + 32] = wb.x; Bt[kc + 1][r0 + 32] = wb.y; Bt[kc + 2][r0 + 32] = wb.z; Bt[kc + 3][r0 + 32] = wb.w;
    __syncthreads();

#pragma unroll
    for (int kk = 0; kk < 32; ++kk) {
      float4 a = *reinterpret_cast<const float4*>(&At[kk][ty * 4]);
      float4 b = *reinterpret_cast<const float4*>(&Bt[kk][tx * 4]);
      acc[0][0] += a.x * b.x; acc[0][1] += a.x * b.y; acc[0][2] += a.x * b.z; acc[0][3] += a.x * b.w;
      acc[1][0] += a.y * b.x; acc[1][1] += a.y * b.y; acc[1][2] += a.y * b.z; acc[1][3] += a.y * b.w;
      acc[2][0] += a.z * b.x; acc[2][1] += a.z * b.y; acc[2][2] += a.z * b.z; acc[2][3] += a.z * b.w;
      acc[3][0] += a.w * b.x; acc[3][1] += a.w * b.y; acc[3][2] += a.w * b.z; acc[3][3] += a.w * b.w;
    }
  }

#pragma unroll
  for (int m = 0; m < 4; ++m) {
    float4 st;
    st.x = acc[m][0]; st.y = acc[m][1]; st.z = acc[m][2]; st.w = acc[m][3];
    *reinterpret_cast<float4*>(&Gz[(size_t)(i0 + ty * 4 + m) * A_ + j0 + tx * 4]) = st;
  }
}

// ---------------------------------------------------------------------------
// Kernel 2: per-anchor 3-NN + Cayley-Menger det. (unchanged)
// ---------------------------------------------------------------------------
__device__ __forceinline__ void lexmin(float& v, int& j, float ov, int oj) {
  if (ov < v || (ov == v && oj < j)) { v = ov; j = oj; }
}

__global__ __launch_bounds__(64) void nn_det_kernel(
    const float* __restrict__ G, const float* __restrict__ sq,
    float* __restrict__ quality) {
  __shared__ float d2s[16];
  const int i = blockIdx.x;
  const int l = threadIdx.x;
  const float sqi = sq[i];
  const int jb = l * 8;

  float gg[8] = {0.f, 0.f, 0.f, 0.f, 0.f, 0.f, 0.f, 0.f};
#pragma unroll
  for (int z = 0; z < KPARTS; ++z) {
    const float* Grow = G + (size_t)z * A_ * A_ + (size_t)i * A_;
    float4 g0 = *reinterpret_cast<const float4*>(&Grow[jb]);
    float4 g1 = *reinterpret_cast<const float4*>(&Grow[jb + 4]);
    gg[0] += g0.x; gg[1] += g0.y; gg[2] += g0.z; gg[3] += g0.w;
    gg[4] += g1.x; gg[5] += g1.y; gg[6] += g1.z; gg[7] += g1.w;
  }
  float4 s0 = *reinterpret_cast<const float4*>(&sq[jb]);
  float4 s1 = *reinterpret_cast<const float4*>(&sq[jb + 4]);
  float ss[8] = { s0.x, s0.y, s0.z, s0.w, s1.x, s1.y, s1.z, s1.w };

  float dist[8];
#pragma unroll
  for (int q = 0; q < 8; ++q) {
    float d2 = fmaxf(sqi + ss[q] - 2.f * gg[q], 0.f);
    float dd = sqrtf(d2);
    if (jb + q == i) dd += 1e12f;
    dist[q] = dd;
  }

  int nn[NN_];
#pragma unroll
  for (int r = 0; r < NN_; ++r) {
    float bv = 1e30f;
    int bi = 0x7fffffff;
#pragma unroll
    for (int q = 0; q < 8; ++q) lexmin(bv, bi, dist[q], jb + q);
#pragma unroll
    for (int d = 1; d < 64; d <<= 1) {
      float ov = __shfl_xor(bv, d);
      int oi = __shfl_xor(bi, d);
      lexmin(bv, bi, ov, oi);
    }
    nn[r] = bi;
#pragma unroll
    for (int q = 0; q < 8; ++q)
      if (jb + q == bi) dist[q] = 1e30f;
  }

  if (l < 16) {
    const int p = l >> 2, q = l & 3;
    const int pi = (p == 0) ? i : ((p == 1) ? nn[0] : ((p == 2) ? nn[1] : nn[2]));
    const int qi = (q == 0) ? i : ((q == 1) ? nn[0] : ((q == 2) ? nn[1] : nn[2]));
    float d2f;
    if (p == q) {
      d2f = 0.f;
    } else {
      float g = 0.f;
#pragma unroll
      for (int z = 0; z < KPARTS; ++z)
        g += G[(size_t)z * A_ * A_ + (size_t)pi * A_ + qi];
      d2f = sq[pi] + sq[qi] - 2.f * g;
    }
    d2s[l] = d2f;
  }
  __syncthreads();

  if (l == 0) {
    double M[5][5];
    M[0][0] = 0.0;
    for (int q = 1; q < 5; ++q) { M[0][q] = 1.0; M[q][0] = 1.0; }
    for (int p = 0; p < 4; ++p)
      for (int q = 0; q < 4; ++q)
        M[p + 1][q + 1] = (double)d2s[p * 4 + q];

    double det = 1.0;
    for (int c = 0; c < 5; ++c) {
      int piv = c;
      double mx = fabs(M[c][c]);
      for (int r2 = c + 1; r2 < 5; ++r2) {
        double v = fabs(M[r2][c]);
        if (v > mx) { mx = v; piv = r2; }
      }
      if (piv != c) {
        for (int c2 = 0; c2 < 5; ++c2) { double tmp = M[c][c2]; M[c][c2] = M[piv][c2]; M[piv][c2] = tmp; }
        det = -det;
      }
      double pv = M[c][c];
      det *= pv;
      if (pv == 0.0) break;
      for (int r2 = c + 1; r2 < 5; ++r2) {
        double f = M[r2][c] / pv;
        for (int c2 = c; c2 < 5; ++c2) M[r2][c2] -= f * M[c][c2];
      }
    }
    float raw = (float)det;
    float sg = (raw > 0.f) ? 1.f : ((raw < 0.f) ? -1.f : 0.f);
    quality[i] = sg * logf(fabsf(raw) + 1e-12f);
  }
}

// ---------------------------------------------------------------------------
// Kernel 3: normalize quality. (unchanged)
// ---------------------------------------------------------------------------
__global__ __launch_bounds__(A_) void norm_cm_kernel(
    const float* __restrict__ quality, float* __restrict__ cmn) {
  __shared__ float red[A_];
  const int t = threadIdx.x;
  float q = quality[t];
  red[t] = q;
  __syncthreads();
  for (int s = A_ / 2; s > 0; s >>= 1) {
    if (t < s) red[t] += red[t + s];
    __syncthreads();
  }
  float mean = red[0] * (1.0f / A_);
  __syncthreads();
  float dq = q - mean;
  red[t] = dq * dq;
  __syncthreads();
  for (int s = A_ / 2; s > 0; s >>= 1) {
    if (t < s) red[t] += red[t + s];
    __syncthreads();
  }
  float sd = sqrtf(red[0] * (1.0f / (A_ - 1)));
  sd = fmaxf(sd, 1e-8f);
  cmn[t] = dq / sd;
}

// ---------------------------------------------------------------------------
// Kernel 4a: RANK ONLY (round-5 proven pipeline), store rank as f32
// (pre-normalized cnt/511). One row per 512-thread block.
// ---------------------------------------------------------------------------
__global__ __launch_bounds__(A_) void rank_kernel(
    const float* __restrict__ tri, float* __restrict__ rankout) {
  __shared__ int hist[256];
  __shared__ int pref[256];
  __shared__ int cursor[256];
  __shared__ unsigned long long sorted[A_];

  const int n = blockIdx.x;
  const int t = threadIdx.x;

  const float ti = tri[(size_t)n * A_ + t];
  const unsigned long long key =
      ((unsigned long long)__float_as_uint(ti) << 9) | (unsigned)t;
  int b = (int)(ti * 128.0f);
  b = (b < 0) ? 0 : ((b > 255) ? 255 : b);

  if (t < 256) { hist[t] = 0; cursor[t] = 0; }
  __syncthreads();
  atomicAdd(&hist[b], 1);
  __syncthreads();

  if (t < 64) {
    const int b4 = t * 4;
    int h0 = hist[b4 + 0], h1 = hist[b4 + 1], h2 = hist[b4 + 2], h3 = hist[b4 + 3];
    int s = h0 + h1 + h2 + h3;
    int incl = s;
#pragma unroll
    for (int d = 1; d < 64; d <<= 1) {
      int u = __shfl_up(incl, d);
      if (t >= d) incl += u;
    }
    int ex = incl - s;
    pref[b4 + 0] = ex;
    pref[b4 + 1] = ex + h0;
    pref[b4 + 2] = ex + h0 + h1;
    pref[b4 + 3] = ex + h0 + h1 + h2;
  }
  __syncthreads();

  const int pos = pref[b] + atomicAdd(&cursor[b], 1);
  sorted[pos] = key;
  __syncthreads();

  const int start = pref[b];
  const int len = hist[b];
  int cnt = start;
  for (int m = 0; m < len; ++m) cnt += (sorted[start + m] < key);

  rankout[(size_t)n * A_ + t] = (float)cnt * (1.0f / (A_ - 1));
}

// ---------------------------------------------------------------------------
// Kernel 4b: MLP ONLY — exact round-8-V2 configuration (the 9 µs one):
// one element per thread, 512-thread blocks, 8192 blocks, scalar loads,
// no LDS, no barriers. Only change: rank from global f32 instead of tid.
// ---------------------------------------------------------------------------
__global__ __launch_bounds__(A_) void mlp_kernel2(
    const float* __restrict__ tri, const float* __restrict__ rankf,
    const float* __restrict__ cmn,
    const float* __restrict__ W1, const float* __restrict__ b1,
    const float* __restrict__ W2, const float* __restrict__ b2,
    float* __restrict__ out) {
  const int n = blockIdx.x;
  const int t = threadIdx.x;
  const size_t idx = (size_t)n * A_ + t;

  const float ti   = tri[idx];
  const float rank = rankf[idx];
  const float f0   = cmn[t];
  const float f1   = 1.0f - ti;

  float logit = b2[0];
#pragma unroll
  for (int k = 0; k < 16; ++k) {
    float x = fmaf(W1[k * 3 + 0], f0,
              fmaf(W1[k * 3 + 1], f1,
              fmaf(W1[k * 3 + 2], rank, b1[k])));
    logit = fmaf(W2[k], gelu_erf_fast(x), logit);
  }
  const float eneg = exp2f(logit * -1.44269504088896340736f);
  out[idx] = __builtin_amdgcn_rcpf(1.0f + eneg);
}

// ---------------------------------------------------------------------------
extern "C" void kernel_launch(void* const* d_in, const int* in_sizes, int n_in,
                              void* d_out, int out_size, void* d_ws, size_t ws_size,
                              hipStream_t stream) {
  // inputs: 0 embedding (unused), 1 anchors, 2 tri, 3 W1, 4 b1, 5 W2, 6 b2
  const float* anchors = (const float*)d_in[1];
  const float* tri     = (const float*)d_in[2];
  const float* W1      = (const float*)d_in[3];
  const float* b1      = (const float*)d_in[4];
  const float* W2      = (const float*)d_in[5];
  const float* b2      = (const float*)d_in[6];
  float* out = (float*)d_out;

  float* G        = (float*)d_ws;                      // KPARTS*A_*A_ (4 MB)
  float* sq       = G + (size_t)KPARTS * A_ * A_;      // A_
  float* quality  = sq + A_;                           // A_
  float* cmn      = quality + A_;                      // A_
  float* rankf    = cmn + A_;                          // N_*A_ f32 (16 MB)

  sq_kernel<<<A_, 64, 0, stream>>>(anchors, sq);
  gram_tiled_kernel<<<dim3(8, 8, KPARTS), dim3(16, 16), 0, stream>>>(anchors, G);
  nn_det_kernel<<<A_, 64, 0, stream>>>(G, sq, quality);
  norm_cm_kernel<<<1, A_, 0, stream>>>(quality, cmn);
  rank_kernel<<<N_, A_, 0, stream>>>(tri, rankf);
  mlp_kernel2<<<N_, A_, 0, stream>>>(tri, rankf, cmn, W1, b1, W2, b2, out);
}

// Round 14
// 77.085 us; speedup vs baseline: 2.3551x; 1.2091x over previous
//
#include <hip/hip_runtime.h>
#include <hip/hip_bf16.h>
#include <math.h>

#define N_ 8192
#define A_ 512
#define D_ 512
#define NN_ 3
#define KPARTS 4

// ---------------------------------------------------------------------------
// tanh-form GELU, algebraically folded:
//   gelu(x) ~= 0.5x(1+tanh(0.7978845608(x+0.044715x^3)))
//            = x - x*r,  r = 1/(1+exp2(c1*x + c3*x^3))
//   c1 = 2*0.7978845608*log2(e) = 2.3022084,  c3 = c1*0.044715 = 0.10294824
// |gelu_tanh - gelu_erf| <= ~1e-3 -> <=3e-4 in sigmoid output (budget 1.9e-2).
// 7 instructions, 2 transcendental.
// ---------------------------------------------------------------------------
__device__ __forceinline__ float gelu_tanh_fast(float x) {
  const float xx = x * x;
  const float u  = x * fmaf(0.10294824f, xx, 2.3022084f);
  const float e  = exp2f(u);
  const float r  = __builtin_amdgcn_rcpf(1.0f + e);
  return fmaf(-x, r, x);
}

// ---------------------------------------------------------------------------
// Kernel 0: sq[i] = ||a_i||^2. (unchanged)
// ---------------------------------------------------------------------------
__global__ __launch_bounds__(64) void sq_kernel(
    const float* __restrict__ anchors, float* __restrict__ sq) {
  const int i = blockIdx.x;
  const int l = threadIdx.x;
  const float4* a = reinterpret_cast<const float4*>(anchors + (size_t)i * D_);
  float s = 0.f;
  for (int k = l; k < D_ / 4; k += 64) {
    float4 v = a[k];
    s += v.x * v.x + v.y * v.y + v.z * v.z + v.w * v.w;
  }
#pragma unroll
  for (int d = 32; d > 0; d >>= 1) s += __shfl_down(s, d);
  if (l == 0) sq[i] = s;
}

// ---------------------------------------------------------------------------
// Kernel 1: G_z = partial gram over K-part z. (unchanged)
// ---------------------------------------------------------------------------
__global__ __launch_bounds__(256) void gram_tiled_kernel(
    const float* __restrict__ anchors, float* __restrict__ G) {
  __shared__ float At[32][68];
  __shared__ float Bt[32][68];

  const int tx = threadIdx.x;
  const int ty = threadIdx.y;
  const int tid = ty * 16 + tx;
  const int i0 = blockIdx.y * 64;
  const int j0 = blockIdx.x * 64;
  const int z  = blockIdx.z;
  float* Gz = G + (size_t)z * A_ * A_;

  const int r0 = tid >> 3;
  const int c4 = tid & 7;

  float acc[4][4];
#pragma unroll
  for (int m = 0; m < 4; ++m)
#pragma unroll
    for (int n = 0; n < 4; ++n) acc[m][n] = 0.f;

  for (int kt = z * (16 / KPARTS); kt < (z + 1) * (16 / KPARTS); ++kt) {
    const int kb = kt * 32 + c4 * 4;
    float4 va = *reinterpret_cast<const float4*>(&anchors[(size_t)(i0 + r0) * D_ + kb]);
    float4 vb = *reinterpret_cast<const float4*>(&anchors[(size_t)(i0 + r0 + 32) * D_ + kb]);
    float4 wa = *reinterpret_cast<const float4*>(&anchors[(size_t)(j0 + r0) * D_ + kb]);
    float4 wb = *reinterpret_cast<const float4*>(&anchors[(size_t)(j0 + r0 + 32) * D_ + kb]);
    __syncthreads();
    const int kc = c4 * 4;
    At[kc + 0][r0] = va.x; At[kc + 1][r0] = va.y; At[kc + 2][r0] = va.z; At[kc + 3][r0] = va.w;
    At[kc + 0][r0 + 32] = vb.x; At[kc + 1][r0 + 32] = vb.y; At[kc + 2][r0 + 32] = vb.z; At[kc + 3][r0 + 32] = vb.w;
    Bt[kc + 0][r0] = wa.x; Bt[kc + 1][r0] = wa.y; Bt[kc + 2][r0] = wa.z; Bt[kc + 3][r0] = wa.w;
    Bt[kc + 0][r0 + 32] = wb.x; Bt[kc + 1][r0 + 32] = wb.y; Bt[kc + 2][r0 + 32] = wb.z; Bt[kc + 3][r0 + 32] = wb.w;
    __syncthreads();

#pragma unroll
    for (int kk = 0; kk < 32; ++kk) {
      float4 a = *reinterpret_cast<const float4*>(&At[kk][ty * 4]);
      float4 b = *reinterpret_cast<const float4*>(&Bt[kk][tx * 4]);
      acc[0][0] += a.x * b.x; acc[0][1] += a.x * b.y; acc[0][2] += a.x * b.z; acc[0][3] += a.x * b.w;
      acc[1][0] += a.y * b.x; acc[1][1] += a.y * b.y; acc[1][2] += a.y * b.z; acc[1][3] += a.y * b.w;
      acc[2][0] += a.z * b.x; acc[2][1] += a.z * b.y; acc[2][2] += a.z * b.z; acc[2][3] += a.z * b.w;
      acc[3][0] += a.w * b.x; acc[3][1] += a.w * b.y; acc[3][2] += a.w * b.z; acc[3][3] += a.w * b.w;
    }
  }

#pragma unroll
  for (int m = 0; m < 4; ++m) {
    float4 st;
    st.x = acc[m][0]; st.y = acc[m][1]; st.z = acc[m][2]; st.w = acc[m][3];
    *reinterpret_cast<float4*>(&Gz[(size_t)(i0 + ty * 4 + m) * A_ + j0 + tx * 4]) = st;
  }
}

// ---------------------------------------------------------------------------
// Kernel 2: per-anchor 3-NN + Cayley-Menger det. (unchanged)
// ---------------------------------------------------------------------------
__device__ __forceinline__ void lexmin(float& v, int& j, float ov, int oj) {
  if (ov < v || (ov == v && oj < j)) { v = ov; j = oj; }
}

__global__ __launch_bounds__(64) void nn_det_kernel(
    const float* __restrict__ G, const float* __restrict__ sq,
    float* __restrict__ quality) {
  __shared__ float d2s[16];
  const int i = blockIdx.x;
  const int l = threadIdx.x;
  const float sqi = sq[i];
  const int jb = l * 8;

  float gg[8] = {0.f, 0.f, 0.f, 0.f, 0.f, 0.f, 0.f, 0.f};
#pragma unroll
  for (int z = 0; z < KPARTS; ++z) {
    const float* Grow = G + (size_t)z * A_ * A_ + (size_t)i * A_;
    float4 g0 = *reinterpret_cast<const float4*>(&Grow[jb]);
    float4 g1 = *reinterpret_cast<const float4*>(&Grow[jb + 4]);
    gg[0] += g0.x; gg[1] += g0.y; gg[2] += g0.z; gg[3] += g0.w;
    gg[4] += g1.x; gg[5] += g1.y; gg[6] += g1.z; gg[7] += g1.w;
  }
  float4 s0 = *reinterpret_cast<const float4*>(&sq[jb]);
  float4 s1 = *reinterpret_cast<const float4*>(&sq[jb + 4]);
  float ss[8] = { s0.x, s0.y, s0.z, s0.w, s1.x, s1.y, s1.z, s1.w };

  float dist[8];
#pragma unroll
  for (int q = 0; q < 8; ++q) {
    float d2 = fmaxf(sqi + ss[q] - 2.f * gg[q], 0.f);
    float dd = sqrtf(d2);
    if (jb + q == i) dd += 1e12f;
    dist[q] = dd;
  }

  int nn[NN_];
#pragma unroll
  for (int r = 0; r < NN_; ++r) {
    float bv = 1e30f;
    int bi = 0x7fffffff;
#pragma unroll
    for (int q = 0; q < 8; ++q) lexmin(bv, bi, dist[q], jb + q);
#pragma unroll
    for (int d = 1; d < 64; d <<= 1) {
      float ov = __shfl_xor(bv, d);
      int oi = __shfl_xor(bi, d);
      lexmin(bv, bi, ov, oi);
    }
    nn[r] = bi;
#pragma unroll
    for (int q = 0; q < 8; ++q)
      if (jb + q == bi) dist[q] = 1e30f;
  }

  if (l < 16) {
    const int p = l >> 2, q = l & 3;
    const int pi = (p == 0) ? i : ((p == 1) ? nn[0] : ((p == 2) ? nn[1] : nn[2]));
    const int qi = (q == 0) ? i : ((q == 1) ? nn[0] : ((q == 2) ? nn[1] : nn[2]));
    float d2f;
    if (p == q) {
      d2f = 0.f;
    } else {
      float g = 0.f;
#pragma unroll
      for (int z = 0; z < KPARTS; ++z)
        g += G[(size_t)z * A_ * A_ + (size_t)pi * A_ + qi];
      d2f = sq[pi] + sq[qi] - 2.f * g;
    }
    d2s[l] = d2f;
  }
  __syncthreads();

  if (l == 0) {
    double M[5][5];
    M[0][0] = 0.0;
    for (int q = 1; q < 5; ++q) { M[0][q] = 1.0; M[q][0] = 1.0; }
    for (int p = 0; p < 4; ++p)
      for (int q = 0; q < 4; ++q)
        M[p + 1][q + 1] = (double)d2s[p * 4 + q];

    double det = 1.0;
    for (int c = 0; c < 5; ++c) {
      int piv = c;
      double mx = fabs(M[c][c]);
      for (int r2 = c + 1; r2 < 5; ++r2) {
        double v = fabs(M[r2][c]);
        if (v > mx) { mx = v; piv = r2; }
      }
      if (piv != c) {
        for (int c2 = 0; c2 < 5; ++c2) { double tmp = M[c][c2]; M[c][c2] = M[piv][c2]; M[piv][c2] = tmp; }
        det = -det;
      }
      double pv = M[c][c];
      det *= pv;
      if (pv == 0.0) break;
      for (int r2 = c + 1; r2 < 5; ++r2) {
        double f = M[r2][c] / pv;
        for (int c2 = c; c2 < 5; ++c2) M[r2][c2] -= f * M[c][c2];
      }
    }
    float raw = (float)det;
    float sg = (raw > 0.f) ? 1.f : ((raw < 0.f) ? -1.f : 0.f);
    quality[i] = sg * logf(fabsf(raw) + 1e-12f);
  }
}

// ---------------------------------------------------------------------------
// Kernel 3: normalize quality. (unchanged)
// ---------------------------------------------------------------------------
__global__ __launch_bounds__(A_) void norm_cm_kernel(
    const float* __restrict__ quality, float* __restrict__ cmn) {
  __shared__ float red[A_];
  const int t = threadIdx.x;
  float q = quality[t];
  red[t] = q;
  __syncthreads();
  for (int s = A_ / 2; s > 0; s >>= 1) {
    if (t < s) red[t] += red[t + s];
    __syncthreads();
  }
  float mean = red[0] * (1.0f / A_);
  __syncthreads();
  float dq = q - mean;
  red[t] = dq * dq;
  __syncthreads();
  for (int s = A_ / 2; s > 0; s >>= 1) {
    if (t < s) red[t] += red[t + s];
    __syncthreads();
  }
  float sd = sqrtf(red[0] * (1.0f / (A_ - 1)));
  sd = fmaxf(sd, 1e-8f);
  cmn[t] = dq / sd;
}

// ---------------------------------------------------------------------------
// Kernel 4a: RANK ONLY (round-5 proven pipeline), store rank as f32.
// (byte-identical to round 13 — measured ~23 µs in this build)
// ---------------------------------------------------------------------------
__global__ __launch_bounds__(A_) void rank_kernel(
    const float* __restrict__ tri, float* __restrict__ rankout) {
  __shared__ int hist[256];
  __shared__ int pref[256];
  __shared__ int cursor[256];
  __shared__ unsigned long long sorted[A_];

  const int n = blockIdx.x;
  const int t = threadIdx.x;

  const float ti = tri[(size_t)n * A_ + t];
  const unsigned long long key =
      ((unsigned long long)__float_as_uint(ti) << 9) | (unsigned)t;
  int b = (int)(ti * 128.0f);
  b = (b < 0) ? 0 : ((b > 255) ? 255 : b);

  if (t < 256) { hist[t] = 0; cursor[t] = 0; }
  __syncthreads();
  atomicAdd(&hist[b], 1);
  __syncthreads();

  if (t < 64) {
    const int b4 = t * 4;
    int h0 = hist[b4 + 0], h1 = hist[b4 + 1], h2 = hist[b4 + 2], h3 = hist[b4 + 3];
    int s = h0 + h1 + h2 + h3;
    int incl = s;
#pragma unroll
    for (int d = 1; d < 64; d <<= 1) {
      int u = __shfl_up(incl, d);
      if (t >= d) incl += u;
    }
    int ex = incl - s;
    pref[b4 + 0] = ex;
    pref[b4 + 1] = ex + h0;
    pref[b4 + 2] = ex + h0 + h1;
    pref[b4 + 3] = ex + h0 + h1 + h2;
  }
  __syncthreads();

  const int pos = pref[b] + atomicAdd(&cursor[b], 1);
  sorted[pos] = key;
  __syncthreads();

  const int start = pref[b];
  const int len = hist[b];
  int cnt = start;
  for (int m = 0; m < len; ++m) cnt += (sorted[start + m] < key);

  rankout[(size_t)n * A_ + t] = (float)cnt * (1.0f / (A_ - 1));
}

// ---------------------------------------------------------------------------
// Kernel 4b: MLP ONLY — same V2-style config (1 elem/thread, 512-thr blocks,
// no LDS/barriers); ONLY change vs round 13: gelu_erf_fast -> gelu_tanh_fast.
// ---------------------------------------------------------------------------
__global__ __launch_bounds__(A_) void mlp_kernel2(
    const float* __restrict__ tri, const float* __restrict__ rankf,
    const float* __restrict__ cmn,
    const float* __restrict__ W1, const float* __restrict__ b1,
    const float* __restrict__ W2, const float* __restrict__ b2,
    float* __restrict__ out) {
  const int n = blockIdx.x;
  const int t = threadIdx.x;
  const size_t idx = (size_t)n * A_ + t;

  const float ti   = tri[idx];
  const float rank = rankf[idx];
  const float f0   = cmn[t];
  const float f1   = 1.0f - ti;

  float logit = b2[0];
#pragma unroll
  for (int k = 0; k < 16; ++k) {
    float x = fmaf(W1[k * 3 + 0], f0,
              fmaf(W1[k * 3 + 1], f1,
              fmaf(W1[k * 3 + 2], rank, b1[k])));
    logit = fmaf(W2[k], gelu_tanh_fast(x), logit);
  }
  const float eneg = exp2f(logit * -1.44269504088896340736f);
  out[idx] = __builtin_amdgcn_rcpf(1.0f + eneg);
}

// ---------------------------------------------------------------------------
extern "C" void kernel_launch(void* const* d_in, const int* in_sizes, int n_in,
                              void* d_out, int out_size, void* d_ws, size_t ws_size,
                              hipStream_t stream) {
  // inputs: 0 embedding (unused), 1 anchors, 2 tri, 3 W1, 4 b1, 5 W2, 6 b2
  const float* anchors = (const float*)d_in[1];
  const float* tri     = (const float*)d_in[2];
  const float* W1      = (const float*)d_in[3];
  const float* b1      = (const float*)d_in[4];
  const float* W2      = (const float*)d_in[5];
  const float* b2      = (const float*)d_in[6];
  float* out = (float*)d_out;

  float* G        = (float*)d_ws;                      // KPARTS*A_*A_ (4 MB)
  float* sq       = G + (size_t)KPARTS * A_ * A_;      // A_
  float* quality  = sq + A_;                           // A_
  float* cmn      = quality + A_;                      // A_
  float* rankf    = cmn + A_;                          // N_*A_ f32 (16 MB)

  sq_kernel<<<A_, 64, 0, stream>>>(anchors, sq);
  gram_tiled_kernel<<<dim3(8, 8, KPARTS), dim3(16, 16), 0, stream>>>(anchors, G);
  nn_det_kernel<<<A_, 64, 0, stream>>>(G, sq, quality);
  norm_cm_kernel<<<1, A_, 0, stream>>>(quality, cmn);
  rank_kernel<<<N_, A_, 0, stream>>>(tri, rankf);
  mlp_kernel2<<<N_, A_, 0, stream>>>(tri, rankf, cmn, W1, b1, W2, b2, out);
}

// Round 15
// 67.888 us; speedup vs baseline: 2.6741x; 1.1355x over previous
//
#include <hip/hip_runtime.h>
#include <hip/hip_bf16.h>
#include <math.h>

#define N_ 8192
#define A_ 512
#define D_ 512
#define NN_ 3
#define KPARTS 4

// ---------------------------------------------------------------------------
// Polynomial GELU — NO transcendentals.
//   gelu(x) = 0.5x + E(|x|),  E(x) = 0.5*x*erf(x/sqrt(2))  (even function)
//   E ~= min(P(min(x^2,9)), 0.5|x|) + 0.5*max(|x|-3, 0)
//   P(u) = u*(a1 + a2 u + a3 u^2 + a4 u^3), quartic fit on u in [0,9].
// Max |err| ~= 9.5e-3 -> output err <= ~3e-3 (budget 1.9e-2). 12 VALU, 0 trans.
// ---------------------------------------------------------------------------
__device__ __forceinline__ float gelu_poly(float x) {
  const float u  = x * x;
  const float s  = fminf(u, 9.0f);
  float p = fmaf(-2.8012e-4f, s, 6.4615e-3f);
  p = fmaf(p, s, -6.1073e-2f);
  p = fmaf(p, s, 3.96693e-1f);
  p = p * s;
  const float ax   = fabsf(x);
  const float e    = fminf(p, 0.5f * ax);
  const float tail = fmaxf(ax - 3.0f, 0.0f);
  return fmaf(0.5f, x, fmaf(0.5f, tail, e));
}

// ---------------------------------------------------------------------------
// Kernel 0: sq[i] = ||a_i||^2. (unchanged)
// ---------------------------------------------------------------------------
__global__ __launch_bounds__(64) void sq_kernel(
    const float* __restrict__ anchors, float* __restrict__ sq) {
  const int i = blockIdx.x;
  const int l = threadIdx.x;
  const float4* a = reinterpret_cast<const float4*>(anchors + (size_t)i * D_);
  float s = 0.f;
  for (int k = l; k < D_ / 4; k += 64) {
    float4 v = a[k];
    s += v.x * v.x + v.y * v.y + v.z * v.z + v.w * v.w;
  }
#pragma unroll
  for (int d = 32; d > 0; d >>= 1) s += __shfl_down(s, d);
  if (l == 0) sq[i] = s;
}

// ---------------------------------------------------------------------------
// Kernel 1: G_z = partial gram over K-part z. (unchanged)
// ---------------------------------------------------------------------------
__global__ __launch_bounds__(256) void gram_tiled_kernel(
    const float* __restrict__ anchors, float* __restrict__ G) {
  __shared__ float At[32][68];
  __shared__ float Bt[32][68];

  const int tx = threadIdx.x;
  const int ty = threadIdx.y;
  const int tid = ty * 16 + tx;
  const int i0 = blockIdx.y * 64;
  const int j0 = blockIdx.x * 64;
  const int z  = blockIdx.z;
  float* Gz = G + (size_t)z * A_ * A_;

  const int r0 = tid >> 3;
  const int c4 = tid & 7;

  float acc[4][4];
#pragma unroll
  for (int m = 0; m < 4; ++m)
#pragma unroll
    for (int n = 0; n < 4; ++n) acc[m][n] = 0.f;

  for (int kt = z * (16 / KPARTS); kt < (z + 1) * (16 / KPARTS); ++kt) {
    const int kb = kt * 32 + c4 * 4;
    float4 va = *reinterpret_cast<const float4*>(&anchors[(size_t)(i0 + r0) * D_ + kb]);
    float4 vb = *reinterpret_cast<const float4*>(&anchors[(size_t)(i0 + r0 + 32) * D_ + kb]);
    float4 wa = *reinterpret_cast<const float4*>(&anchors[(size_t)(j0 + r0) * D_ + kb]);
    float4 wb = *reinterpret_cast<const float4*>(&anchors[(size_t)(j0 + r0 + 32) * D_ + kb]);
    __syncthreads();
    const int kc = c4 * 4;
    At[kc + 0][r0] = va.x; At[kc + 1][r0] = va.y; At[kc + 2][r0] = va.z; At[kc + 3][r0] = va.w;
    At[kc + 0][r0 + 32] = vb.x; At[kc + 1][r0 + 32] = vb.y; At[kc + 2][r0 + 32] = vb.z; At[kc + 3][r0 + 32] = vb.w;
    Bt[kc + 0][r0] = wa.x; Bt[kc + 1][r0] = wa.y; Bt[kc + 2][r0] = wa.z; Bt[kc + 3][r0] = wa.w;
    Bt[kc + 0][r0 + 32] = wb.x; Bt[kc + 1][r0 + 32] = wb.y; Bt[kc + 2][r0 + 32] = wb.z; Bt[kc + 3][r0 + 32] = wb.w;
    __syncthreads();

#pragma unroll
    for (int kk = 0; kk < 32; ++kk) {
      float4 a = *reinterpret_cast<const float4*>(&At[kk][ty * 4]);
      float4 b = *reinterpret_cast<const float4*>(&Bt[kk][tx * 4]);
      acc[0][0] += a.x * b.x; acc[0][1] += a.x * b.y; acc[0][2] += a.x * b.z; acc[0][3] += a.x * b.w;
      acc[1][0] += a.y * b.x; acc[1][1] += a.y * b.y; acc[1][2] += a.y * b.z; acc[1][3] += a.y * b.w;
      acc[2][0] += a.z * b.x; acc[2][1] += a.z * b.y; acc[2][2] += a.z * b.z; acc[2][3] += a.z * b.w;
      acc[3][0] += a.w * b.x; acc[3][1] += a.w * b.y; acc[3][2] += a.w * b.z; acc[3][3] += a.w * b.w;
    }
  }

#pragma unroll
  for (int m = 0; m < 4; ++m) {
    float4 st;
    st.x = acc[m][0]; st.y = acc[m][1]; st.z = acc[m][2]; st.w = acc[m][3];
    *reinterpret_cast<float4*>(&Gz[(size_t)(i0 + ty * 4 + m) * A_ + j0 + tx * 4]) = st;
  }
}

// ---------------------------------------------------------------------------
// Kernel 2: per-anchor 3-NN + Cayley-Menger det. (unchanged)
// ---------------------------------------------------------------------------
__device__ __forceinline__ void lexmin(float& v, int& j, float ov, int oj) {
  if (ov < v || (ov == v && oj < j)) { v = ov; j = oj; }
}

__global__ __launch_bounds__(64) void nn_det_kernel(
    const float* __restrict__ G, const float* __restrict__ sq,
    float* __restrict__ quality) {
  __shared__ float d2s[16];
  const int i = blockIdx.x;
  const int l = threadIdx.x;
  const float sqi = sq[i];
  const int jb = l * 8;

  float gg[8] = {0.f, 0.f, 0.f, 0.f, 0.f, 0.f, 0.f, 0.f};
#pragma unroll
  for (int z = 0; z < KPARTS; ++z) {
    const float* Grow = G + (size_t)z * A_ * A_ + (size_t)i * A_;
    float4 g0 = *reinterpret_cast<const float4*>(&Grow[jb]);
    float4 g1 = *reinterpret_cast<const float4*>(&Grow[jb + 4]);
    gg[0] += g0.x; gg[1] += g0.y; gg[2] += g0.z; gg[3] += g0.w;
    gg[4] += g1.x; gg[5] += g1.y; gg[6] += g1.z; gg[7] += g1.w;
  }
  float4 s0 = *reinterpret_cast<const float4*>(&sq[jb]);
  float4 s1 = *reinterpret_cast<const float4*>(&sq[jb + 4]);
  float ss[8] = { s0.x, s0.y, s0.z, s0.w, s1.x, s1.y, s1.z, s1.w };

  float dist[8];
#pragma unroll
  for (int q = 0; q < 8; ++q) {
    float d2 = fmaxf(sqi + ss[q] - 2.f * gg[q], 0.f);
    float dd = sqrtf(d2);
    if (jb + q == i) dd += 1e12f;
    dist[q] = dd;
  }

  int nn[NN_];
#pragma unroll
  for (int r = 0; r < NN_; ++r) {
    float bv = 1e30f;
    int bi = 0x7fffffff;
#pragma unroll
    for (int q = 0; q < 8; ++q) lexmin(bv, bi, dist[q], jb + q);
#pragma unroll
    for (int d = 1; d < 64; d <<= 1) {
      float ov = __shfl_xor(bv, d);
      int oi = __shfl_xor(bi, d);
      lexmin(bv, bi, ov, oi);
    }
    nn[r] = bi;
#pragma unroll
    for (int q = 0; q < 8; ++q)
      if (jb + q == bi) dist[q] = 1e30f;
  }

  if (l < 16) {
    const int p = l >> 2, q = l & 3;
    const int pi = (p == 0) ? i : ((p == 1) ? nn[0] : ((p == 2) ? nn[1] : nn[2]));
    const int qi = (q == 0) ? i : ((q == 1) ? nn[0] : ((q == 2) ? nn[1] : nn[2]));
    float d2f;
    if (p == q) {
      d2f = 0.f;
    } else {
      float g = 0.f;
#pragma unroll
      for (int z = 0; z < KPARTS; ++z)
        g += G[(size_t)z * A_ * A_ + (size_t)pi * A_ + qi];
      d2f = sq[pi] + sq[qi] - 2.f * g;
    }
    d2s[l] = d2f;
  }
  __syncthreads();

  if (l == 0) {
    double M[5][5];
    M[0][0] = 0.0;
    for (int q = 1; q < 5; ++q) { M[0][q] = 1.0; M[q][0] = 1.0; }
    for (int p = 0; p < 4; ++p)
      for (int q = 0; q < 4; ++q)
        M[p + 1][q + 1] = (double)d2s[p * 4 + q];

    double det = 1.0;
    for (int c = 0; c < 5; ++c) {
      int piv = c;
      double mx = fabs(M[c][c]);
      for (int r2 = c + 1; r2 < 5; ++r2) {
        double v = fabs(M[r2][c]);
        if (v > mx) { mx = v; piv = r2; }
      }
      if (piv != c) {
        for (int c2 = 0; c2 < 5; ++c2) { double tmp = M[c][c2]; M[c][c2] = M[piv][c2]; M[piv][c2] = tmp; }
        det = -det;
      }
      double pv = M[c][c];
      det *= pv;
      if (pv == 0.0) break;
      for (int r2 = c + 1; r2 < 5; ++r2) {
        double f = M[r2][c] / pv;
        for (int c2 = c; c2 < 5; ++c2) M[r2][c2] -= f * M[c][c2];
      }
    }
    float raw = (float)det;
    float sg = (raw > 0.f) ? 1.f : ((raw < 0.f) ? -1.f : 0.f);
    quality[i] = sg * logf(fabsf(raw) + 1e-12f);
  }
}

// ---------------------------------------------------------------------------
// Kernel 3: normalize quality. (unchanged)
// ---------------------------------------------------------------------------
__global__ __launch_bounds__(A_) void norm_cm_kernel(
    const float* __restrict__ quality, float* __restrict__ cmn) {
  __shared__ float red[A_];
  const int t = threadIdx.x;
  float q = quality[t];
  red[t] = q;
  __syncthreads();
  for (int s = A_ / 2; s > 0; s >>= 1) {
    if (t < s) red[t] += red[t + s];
    __syncthreads();
  }
  float mean = red[0] * (1.0f / A_);
  __syncthreads();
  float dq = q - mean;
  red[t] = dq * dq;
  __syncthreads();
  for (int s = A_ / 2; s > 0; s >>= 1) {
    if (t < s) red[t] += red[t + s];
    __syncthreads();
  }
  float sd = sqrtf(red[0] * (1.0f / (A_ - 1)));
  sd = fmaxf(sd, 1e-8f);
  cmn[t] = dq / sd;
}

// ---------------------------------------------------------------------------
// Kernel 4a: RANK ONLY (round-5 proven pipeline), store rank as f32.
// (byte-identical to round 13/14 — measured ~23 µs in this build)
// ---------------------------------------------------------------------------
__global__ __launch_bounds__(A_) void rank_kernel(
    const float* __restrict__ tri, float* __restrict__ rankout) {
  __shared__ int hist[256];
  __shared__ int pref[256];
  __shared__ int cursor[256];
  __shared__ unsigned long long sorted[A_];

  const int n = blockIdx.x;
  const int t = threadIdx.x;

  const float ti = tri[(size_t)n * A_ + t];
  const unsigned long long key =
      ((unsigned long long)__float_as_uint(ti) << 9) | (unsigned)t;
  int b = (int)(ti * 128.0f);
  b = (b < 0) ? 0 : ((b > 255) ? 255 : b);

  if (t < 256) { hist[t] = 0; cursor[t] = 0; }
  __syncthreads();
  atomicAdd(&hist[b], 1);
  __syncthreads();

  if (t < 64) {
    const int b4 = t * 4;
    int h0 = hist[b4 + 0], h1 = hist[b4 + 1], h2 = hist[b4 + 2], h3 = hist[b4 + 3];
    int s = h0 + h1 + h2 + h3;
    int incl = s;
#pragma unroll
    for (int d = 1; d < 64; d <<= 1) {
      int u = __shfl_up(incl, d);
      if (t >= d) incl += u;
    }
    int ex = incl - s;
    pref[b4 + 0] = ex;
    pref[b4 + 1] = ex + h0;
    pref[b4 + 2] = ex + h0 + h1;
    pref[b4 + 3] = ex + h0 + h1 + h2;
  }
  __syncthreads();

  const int pos = pref[b] + atomicAdd(&cursor[b], 1);
  sorted[pos] = key;
  __syncthreads();

  const int start = pref[b];
  const int len = hist[b];
  int cnt = start;
  for (int m = 0; m < len; ++m) cnt += (sorted[start + m] < key);

  rankout[(size_t)n * A_ + t] = (float)cnt * (1.0f / (A_ - 1));
}

// ---------------------------------------------------------------------------
// Kernel 4b: MLP ONLY — same config as round 14; ONLY change:
// gelu_tanh_fast -> gelu_poly (zero inner-loop transcendentals).
// ---------------------------------------------------------------------------
__global__ __launch_bounds__(A_) void mlp_kernel2(
    const float* __restrict__ tri, const float* __restrict__ rankf,
    const float* __restrict__ cmn,
    const float* __restrict__ W1, const float* __restrict__ b1,
    const float* __restrict__ W2, const float* __restrict__ b2,
    float* __restrict__ out) {
  const int n = blockIdx.x;
  const int t = threadIdx.x;
  const size_t idx = (size_t)n * A_ + t;

  const float ti   = tri[idx];
  const float rank = rankf[idx];
  const float f0   = cmn[t];
  const float f1   = 1.0f - ti;

  float logit = b2[0];
#pragma unroll
  for (int k = 0; k < 16; ++k) {
    float x = fmaf(W1[k * 3 + 0], f0,
              fmaf(W1[k * 3 + 1], f1,
              fmaf(W1[k * 3 + 2], rank, b1[k])));
    logit = fmaf(W2[k], gelu_poly(x), logit);
  }
  const float eneg = exp2f(logit * -1.44269504088896340736f);
  out[idx] = __builtin_amdgcn_rcpf(1.0f + eneg);
}

// ---------------------------------------------------------------------------
extern "C" void kernel_launch(void* const* d_in, const int* in_sizes, int n_in,
                              void* d_out, int out_size, void* d_ws, size_t ws_size,
                              hipStream_t stream) {
  // inputs: 0 embedding (unused), 1 anchors, 2 tri, 3 W1, 4 b1, 5 W2, 6 b2
  const float* anchors = (const float*)d_in[1];
  const float* tri     = (const float*)d_in[2];
  const float* W1      = (const float*)d_in[3];
  const float* b1      = (const float*)d_in[4];
  const float* W2      = (const float*)d_in[5];
  const float* b2      = (const float*)d_in[6];
  float* out = (float*)d_out;

  float* G        = (float*)d_ws;                      // KPARTS*A_*A_ (4 MB)
  float* sq       = G + (size_t)KPARTS * A_ * A_;      // A_
  float* quality  = sq + A_;                           // A_
  float* cmn      = quality + A_;                      // A_
  float* rankf    = cmn + A_;                          // N_*A_ f32 (16 MB)

  sq_kernel<<<A_, 64, 0, stream>>>(anchors, sq);
  gram_tiled_kernel<<<dim3(8, 8, KPARTS), dim3(16, 16), 0, stream>>>(anchors, G);
  nn_det_kernel<<<A_, 64, 0, stream>>>(G, sq, quality);
  norm_cm_kernel<<<1, A_, 0, stream>>>(quality, cmn);
  rank_kernel<<<N_, A_, 0, stream>>>(tri, rankf);
  mlp_kernel2<<<N_, A_, 0, stream>>>(tri, rankf, cmn, W1, b1, W2, b2, out);
}

// Round 16
// 63.467 us; speedup vs baseline: 2.8604x; 1.0697x over previous
//
#include <hip/hip_runtime.h>
#include <hip/hip_bf16.h>
#include <math.h>

#define N_ 8192
#define A_ 512
#define D_ 512
#define NN_ 3
#define KPARTS 4

// ---------------------------------------------------------------------------
// Polynomial GELU — NO transcendentals. (unchanged from round 15; |err|<=9.5e-3)
// ---------------------------------------------------------------------------
__device__ __forceinline__ float gelu_poly(float x) {
  const float u  = x * x;
  const float s  = fminf(u, 9.0f);
  float p = fmaf(-2.8012e-4f, s, 6.4615e-3f);
  p = fmaf(p, s, -6.1073e-2f);
  p = fmaf(p, s, 3.96693e-1f);
  p = p * s;
  const float ax   = fabsf(x);
  const float e    = fminf(p, 0.5f * ax);
  const float tail = fmaxf(ax - 3.0f, 0.0f);
  return fmaf(0.5f, x, fmaf(0.5f, tail, e));
}

// ---------------------------------------------------------------------------
// Kernel 0: sq[i] = ||a_i||^2. (unchanged)
// ---------------------------------------------------------------------------
__global__ __launch_bounds__(64) void sq_kernel(
    const float* __restrict__ anchors, float* __restrict__ sq) {
  const int i = blockIdx.x;
  const int l = threadIdx.x;
  const float4* a = reinterpret_cast<const float4*>(anchors + (size_t)i * D_);
  float s = 0.f;
  for (int k = l; k < D_ / 4; k += 64) {
    float4 v = a[k];
    s += v.x * v.x + v.y * v.y + v.z * v.z + v.w * v.w;
  }
#pragma unroll
  for (int d = 32; d > 0; d >>= 1) s += __shfl_down(s, d);
  if (l == 0) sq[i] = s;
}

// ---------------------------------------------------------------------------
// Kernel 1: G_z = partial gram over K-part z. (unchanged)
// ---------------------------------------------------------------------------
__global__ __launch_bounds__(256) void gram_tiled_kernel(
    const float* __restrict__ anchors, float* __restrict__ G) {
  __shared__ float At[32][68];
  __shared__ float Bt[32][68];

  const int tx = threadIdx.x;
  const int ty = threadIdx.y;
  const int tid = ty * 16 + tx;
  const int i0 = blockIdx.y * 64;
  const int j0 = blockIdx.x * 64;
  const int z  = blockIdx.z;
  float* Gz = G + (size_t)z * A_ * A_;

  const int r0 = tid >> 3;
  const int c4 = tid & 7;

  float acc[4][4];
#pragma unroll
  for (int m = 0; m < 4; ++m)
#pragma unroll
    for (int n = 0; n < 4; ++n) acc[m][n] = 0.f;

  for (int kt = z * (16 / KPARTS); kt < (z + 1) * (16 / KPARTS); ++kt) {
    const int kb = kt * 32 + c4 * 4;
    float4 va = *reinterpret_cast<const float4*>(&anchors[(size_t)(i0 + r0) * D_ + kb]);
    float4 vb = *reinterpret_cast<const float4*>(&anchors[(size_t)(i0 + r0 + 32) * D_ + kb]);
    float4 wa = *reinterpret_cast<const float4*>(&anchors[(size_t)(j0 + r0) * D_ + kb]);
    float4 wb = *reinterpret_cast<const float4*>(&anchors[(size_t)(j0 + r0 + 32) * D_ + kb]);
    __syncthreads();
    const int kc = c4 * 4;
    At[kc + 0][r0] = va.x; At[kc + 1][r0] = va.y; At[kc + 2][r0] = va.z; At[kc + 3][r0] = va.w;
    At[kc + 0][r0 + 32] = vb.x; At[kc + 1][r0 + 32] = vb.y; At[kc + 2][r0 + 32] = vb.z; At[kc + 3][r0 + 32] = vb.w;
    Bt[kc + 0][r0] = wa.x; Bt[kc + 1][r0] = wa.y; Bt[kc + 2][r0] = wa.z; Bt[kc + 3][r0] = wa.w;
    Bt[kc + 0][r0 + 32] = wb.x; Bt[kc + 1][r0 + 32] = wb.y; Bt[kc + 2][r0 + 32] = wb.z; Bt[kc + 3][r0 + 32] = wb.w;
    __syncthreads();

#pragma unroll
    for (int kk = 0; kk < 32; ++kk) {
      float4 a = *reinterpret_cast<const float4*>(&At[kk][ty * 4]);
      float4 b = *reinterpret_cast<const float4*>(&Bt[kk][tx * 4]);
      acc[0][0] += a.x * b.x; acc[0][1] += a.x * b.y; acc[0][2] += a.x * b.z; acc[0][3] += a.x * b.w;
      acc[1][0] += a.y * b.x; acc[1][1] += a.y * b.y; acc[1][2] += a.y * b.z; acc[1][3] += a.y * b.w;
      acc[2][0] += a.z * b.x; acc[2][1] += a.z * b.y; acc[2][2] += a.z * b.z; acc[2][3] += a.z * b.w;
      acc[3][0] += a.w * b.x; acc[3][1] += a.w * b.y; acc[3][2] += a.w * b.z; acc[3][3] += a.w * b.w;
    }
  }

#pragma unroll
  for (int m = 0; m < 4; ++m) {
    float4 st;
    st.x = acc[m][0]; st.y = acc[m][1]; st.z = acc[m][2]; st.w = acc[m][3];
    *reinterpret_cast<float4*>(&Gz[(size_t)(i0 + ty * 4 + m) * A_ + j0 + tx * 4]) = st;
  }
}

// ---------------------------------------------------------------------------
// Kernel 2: per-anchor 3-NN + Cayley-Menger det. (unchanged)
// ---------------------------------------------------------------------------
__device__ __forceinline__ void lexmin(float& v, int& j, float ov, int oj) {
  if (ov < v || (ov == v && oj < j)) { v = ov; j = oj; }
}

__global__ __launch_bounds__(64) void nn_det_kernel(
    const float* __restrict__ G, const float* __restrict__ sq,
    float* __restrict__ quality) {
  __shared__ float d2s[16];
  const int i = blockIdx.x;
  const int l = threadIdx.x;
  const float sqi = sq[i];
  const int jb = l * 8;

  float gg[8] = {0.f, 0.f, 0.f, 0.f, 0.f, 0.f, 0.f, 0.f};
#pragma unroll
  for (int z = 0; z < KPARTS; ++z) {
    const float* Grow = G + (size_t)z * A_ * A_ + (size_t)i * A_;
    float4 g0 = *reinterpret_cast<const float4*>(&Grow[jb]);
    float4 g1 = *reinterpret_cast<const float4*>(&Grow[jb + 4]);
    gg[0] += g0.x; gg[1] += g0.y; gg[2] += g0.z; gg[3] += g0.w;
    gg[4] += g1.x; gg[5] += g1.y; gg[6] += g1.z; gg[7] += g1.w;
  }
  float4 s0 = *reinterpret_cast<const float4*>(&sq[jb]);
  float4 s1 = *reinterpret_cast<const float4*>(&sq[jb + 4]);
  float ss[8] = { s0.x, s0.y, s0.z, s0.w, s1.x, s1.y, s1.z, s1.w };

  float dist[8];
#pragma unroll
  for (int q = 0; q < 8; ++q) {
    float d2 = fmaxf(sqi + ss[q] - 2.f * gg[q], 0.f);
    float dd = sqrtf(d2);
    if (jb + q == i) dd += 1e12f;
    dist[q] = dd;
  }

  int nn[NN_];
#pragma unroll
  for (int r = 0; r < NN_; ++r) {
    float bv = 1e30f;
    int bi = 0x7fffffff;
#pragma unroll
    for (int q = 0; q < 8; ++q) lexmin(bv, bi, dist[q], jb + q);
#pragma unroll
    for (int d = 1; d < 64; d <<= 1) {
      float ov = __shfl_xor(bv, d);
      int oi = __shfl_xor(bi, d);
      lexmin(bv, bi, ov, oi);
    }
    nn[r] = bi;
#pragma unroll
    for (int q = 0; q < 8; ++q)
      if (jb + q == bi) dist[q] = 1e30f;
  }

  if (l < 16) {
    const int p = l >> 2, q = l & 3;
    const int pi = (p == 0) ? i : ((p == 1) ? nn[0] : ((p == 2) ? nn[1] : nn[2]));
    const int qi = (q == 0) ? i : ((q == 1) ? nn[0] : ((q == 2) ? nn[1] : nn[2]));
    float d2f;
    if (p == q) {
      d2f = 0.f;
    } else {
      float g = 0.f;
#pragma unroll
      for (int z = 0; z < KPARTS; ++z)
        g += G[(size_t)z * A_ * A_ + (size_t)pi * A_ + qi];
      d2f = sq[pi] + sq[qi] - 2.f * g;
    }
    d2s[l] = d2f;
  }
  __syncthreads();

  if (l == 0) {
    double M[5][5];
    M[0][0] = 0.0;
    for (int q = 1; q < 5; ++q) { M[0][q] = 1.0; M[q][0] = 1.0; }
    for (int p = 0; p < 4; ++p)
      for (int q = 0; q < 4; ++q)
        M[p + 1][q + 1] = (double)d2s[p * 4 + q];

    double det = 1.0;
    for (int c = 0; c < 5; ++c) {
      int piv = c;
      double mx = fabs(M[c][c]);
      for (int r2 = c + 1; r2 < 5; ++r2) {
        double v = fabs(M[r2][c]);
        if (v > mx) { mx = v; piv = r2; }
      }
      if (piv != c) {
        for (int c2 = 0; c2 < 5; ++c2) { double tmp = M[c][c2]; M[c][c2] = M[piv][c2]; M[piv][c2] = tmp; }
        det = -det;
      }
      double pv = M[c][c];
      det *= pv;
      if (pv == 0.0) break;
      for (int r2 = c + 1; r2 < 5; ++r2) {
        double f = M[r2][c] / pv;
        for (int c2 = c; c2 < 5; ++c2) M[r2][c2] -= f * M[c][c2];
      }
    }
    float raw = (float)det;
    float sg = (raw > 0.f) ? 1.f : ((raw < 0.f) ? -1.f : 0.f);
    quality[i] = sg * logf(fabsf(raw) + 1e-12f);
  }
}

// ---------------------------------------------------------------------------
// Kernel 3: normalize quality. (unchanged)
// ---------------------------------------------------------------------------
__global__ __launch_bounds__(A_) void norm_cm_kernel(
    const float* __restrict__ quality, float* __restrict__ cmn) {
  __shared__ float red[A_];
  const int t = threadIdx.x;
  float q = quality[t];
  red[t] = q;
  __syncthreads();
  for (int s = A_ / 2; s > 0; s >>= 1) {
    if (t < s) red[t] += red[t + s];
    __syncthreads();
  }
  float mean = red[0] * (1.0f / A_);
  __syncthreads();
  float dq = q - mean;
  red[t] = dq * dq;
  __syncthreads();
  for (int s = A_ / 2; s > 0; s >>= 1) {
    if (t < s) red[t] += red[t + s];
    __syncthreads();
  }
  float sd = sqrtf(red[0] * (1.0f / (A_ - 1)));
  sd = fmaxf(sd, 1e-8f);
  cmn[t] = dq / sd;
}

// ---------------------------------------------------------------------------
// Kernel 4: FUSED rank + poly-MLP + sigmoid (round-5 rank structure verbatim,
// gelu_poly MLP appended; no rankf round-trip, one dispatch).
// ---------------------------------------------------------------------------
__global__ __launch_bounds__(A_) void gate_fused(
    const float* __restrict__ tri, const float* __restrict__ cmn,
    const float* __restrict__ W1, const float* __restrict__ b1,
    const float* __restrict__ W2, const float* __restrict__ b2,
    float* __restrict__ out) {
  __shared__ int hist[256];
  __shared__ int pref[256];
  __shared__ int cursor[256];
  __shared__ unsigned long long sorted[A_];

  const int n = blockIdx.x;
  const int t = threadIdx.x;

  const float ti = tri[(size_t)n * A_ + t];
  const unsigned long long key =
      ((unsigned long long)__float_as_uint(ti) << 9) | (unsigned)t;
  int b = (int)(ti * 128.0f);
  b = (b < 0) ? 0 : ((b > 255) ? 255 : b);

  if (t < 256) { hist[t] = 0; cursor[t] = 0; }
  __syncthreads();
  atomicAdd(&hist[b], 1);
  __syncthreads();

  if (t < 64) {
    const int b4 = t * 4;
    int h0 = hist[b4 + 0], h1 = hist[b4 + 1], h2 = hist[b4 + 2], h3 = hist[b4 + 3];
    int s = h0 + h1 + h2 + h3;
    int incl = s;
#pragma unroll
    for (int d = 1; d < 64; d <<= 1) {
      int u = __shfl_up(incl, d);
      if (t >= d) incl += u;
    }
    int ex = incl - s;
    pref[b4 + 0] = ex;
    pref[b4 + 1] = ex + h0;
    pref[b4 + 2] = ex + h0 + h1;
    pref[b4 + 3] = ex + h0 + h1 + h2;
  }
  __syncthreads();

  const int pos = pref[b] + atomicAdd(&cursor[b], 1);
  sorted[pos] = key;
  __syncthreads();

  const int start = pref[b];
  const int len = hist[b];
  int cnt = start;
  for (int m = 0; m < len; ++m) cnt += (sorted[start + m] < key);
  const float rank = (float)cnt * (1.0f / (A_ - 1));

  const float f0 = cmn[t];
  const float f1 = 1.0f - ti;

  float logit = b2[0];
#pragma unroll
  for (int k = 0; k < 16; ++k) {
    float x = fmaf(W1[k * 3 + 0], f0,
              fmaf(W1[k * 3 + 1], f1,
              fmaf(W1[k * 3 + 2], rank, b1[k])));
    logit = fmaf(W2[k], gelu_poly(x), logit);
  }
  const float eneg = exp2f(logit * -1.44269504088896340736f);
  out[(size_t)n * A_ + t] = __builtin_amdgcn_rcpf(1.0f + eneg);
}

// ---------------------------------------------------------------------------
extern "C" void kernel_launch(void* const* d_in, const int* in_sizes, int n_in,
                              void* d_out, int out_size, void* d_ws, size_t ws_size,
                              hipStream_t stream) {
  // inputs: 0 embedding (unused), 1 anchors, 2 tri, 3 W1, 4 b1, 5 W2, 6 b2
  const float* anchors = (const float*)d_in[1];
  const float* tri     = (const float*)d_in[2];
  const float* W1      = (const float*)d_in[3];
  const float* b1      = (const float*)d_in[4];
  const float* W2      = (const float*)d_in[5];
  const float* b2      = (const float*)d_in[6];
  float* out = (float*)d_out;

  float* G        = (float*)d_ws;                      // KPARTS*A_*A_ (4 MB)
  float* sq       = G + (size_t)KPARTS * A_ * A_;      // A_
  float* quality  = sq + A_;                           // A_
  float* cmn      = quality + A_;                      // A_

  sq_kernel<<<A_, 64, 0, stream>>>(anchors, sq);
  gram_tiled_kernel<<<dim3(8, 8, KPARTS), dim3(16, 16), 0, stream>>>(anchors, G);
  nn_det_kernel<<<A_, 64, 0, stream>>>(G, sq, quality);
  norm_cm_kernel<<<1, A_, 0, stream>>>(quality, cmn);
  gate_fused<<<N_, A_, 0, stream>>>(tri, cmn, W1, b1, W2, b2, out);
}

// Round 17
// 62.113 us; speedup vs baseline: 2.9228x; 1.0218x over previous
//
#include <hip/hip_runtime.h>
#include <hip/hip_bf16.h>
#include <math.h>

#define N_ 8192
#define A_ 512
#define D_ 512
#define NN_ 3
#define KPARTS 8

typedef float v2f __attribute__((ext_vector_type(2)));

// ---------------------------------------------------------------------------
// Packed polynomial GELU (2 lanes via v_pk_* f32 ops). Same poly as round 15:
//   gelu(x) = 0.5x + min(P(min(x^2,9)), 0.5|x|) + 0.5*max(|x|-3,0)
// |err| <= 9.5e-3. Mul/add contract to v_pk_fma_f32 on gfx950.
// ---------------------------------------------------------------------------
__device__ __forceinline__ v2f gelu_poly2(v2f x) {
  const v2f u = x * x;
  v2f nine; nine.x = 9.0f; nine.y = 9.0f;
  v2f zero; zero.x = 0.0f; zero.y = 0.0f;
  const v2f s = __builtin_elementwise_min(u, nine);
  v2f p = -2.8012e-4f * s + 6.4615e-3f;
  p = p * s + -6.1073e-2f;
  p = p * s + 3.96693e-1f;
  p = p * s;
  const v2f ax = __builtin_elementwise_abs(x);
  const v2f e = __builtin_elementwise_min(p, 0.5f * ax);
  const v2f tail = __builtin_elementwise_max(ax - 3.0f, zero);
  return 0.5f * x + (0.5f * tail + e);
}

// ---------------------------------------------------------------------------
// Kernel 0: sq[i] = ||a_i||^2. (unchanged)
// ---------------------------------------------------------------------------
__global__ __launch_bounds__(64) void sq_kernel(
    const float* __restrict__ anchors, float* __restrict__ sq) {
  const int i = blockIdx.x;
  const int l = threadIdx.x;
  const float4* a = reinterpret_cast<const float4*>(anchors + (size_t)i * D_);
  float s = 0.f;
  for (int k = l; k < D_ / 4; k += 64) {
    float4 v = a[k];
    s += v.x * v.x + v.y * v.y + v.z * v.z + v.w * v.w;
  }
#pragma unroll
  for (int d = 32; d > 0; d >>= 1) s += __shfl_down(s, d);
  if (l == 0) sq[i] = s;
}

// ---------------------------------------------------------------------------
// Kernel 1: G_z = partial gram over K-part z. KPARTS=8 -> 512 blocks
// (2 blocks/CU) for better latency overlap in the staging loop.
// ---------------------------------------------------------------------------
__global__ __launch_bounds__(256) void gram_tiled_kernel(
    const float* __restrict__ anchors, float* __restrict__ G) {
  __shared__ float At[32][68];
  __shared__ float Bt[32][68];

  const int tx = threadIdx.x;
  const int ty = threadIdx.y;
  const int tid = ty * 16 + tx;
  const int i0 = blockIdx.y * 64;
  const int j0 = blockIdx.x * 64;
  const int z  = blockIdx.z;
  float* Gz = G + (size_t)z * A_ * A_;

  const int r0 = tid >> 3;
  const int c4 = tid & 7;

  float acc[4][4];
#pragma unroll
  for (int m = 0; m < 4; ++m)
#pragma unroll
    for (int n = 0; n < 4; ++n) acc[m][n] = 0.f;

  for (int kt = z * (16 / KPARTS); kt < (z + 1) * (16 / KPARTS); ++kt) {
    const int kb = kt * 32 + c4 * 4;
    float4 va = *reinterpret_cast<const float4*>(&anchors[(size_t)(i0 + r0) * D_ + kb]);
    float4 vb = *reinterpret_cast<const float4*>(&anchors[(size_t)(i0 + r0 + 32) * D_ + kb]);
    float4 wa = *reinterpret_cast<const float4*>(&anchors[(size_t)(j0 + r0) * D_ + kb]);
    float4 wb = *reinterpret_cast<const float4*>(&anchors[(size_t)(j0 + r0 + 32) * D_ + kb]);
    __syncthreads();
    const int kc = c4 * 4;
    At[kc + 0][r0] = va.x; At[kc + 1][r0] = va.y; At[kc + 2][r0] = va.z; At[kc + 3][r0] = va.w;
    At[kc + 0][r0 + 32] = vb.x; At[kc + 1][r0 + 32] = vb.y; At[kc + 2][r0 + 32] = vb.z; At[kc + 3][r0 + 32] = vb.w;
    Bt[kc + 0][r0] = wa.x; Bt[kc + 1][r0] = wa.y; Bt[kc + 2][r0] = wa.z; Bt[kc + 3][r0] = wa.w;
    Bt[kc + 0][r0 + 32] = wb.x; Bt[kc + 1][r0 + 32] = wb.y; Bt[kc + 2][r0 + 32] = wb.z; Bt[kc + 3][r0 + 32] = wb.w;
    __syncthreads();

#pragma unroll
    for (int kk = 0; kk < 32; ++kk) {
      float4 a = *reinterpret_cast<const float4*>(&At[kk][ty * 4]);
      float4 b = *reinterpret_cast<const float4*>(&Bt[kk][tx * 4]);
      acc[0][0] += a.x * b.x; acc[0][1] += a.x * b.y; acc[0][2] += a.x * b.z; acc[0][3] += a.x * b.w;
      acc[1][0] += a.y * b.x; acc[1][1] += a.y * b.y; acc[1][2] += a.y * b.z; acc[1][3] += a.y * b.w;
      acc[2][0] += a.z * b.x; acc[2][1] += a.z * b.y; acc[2][2] += a.z * b.z; acc[2][3] += a.z * b.w;
      acc[3][0] += a.w * b.x; acc[3][1] += a.w * b.y; acc[3][2] += a.w * b.z; acc[3][3] += a.w * b.w;
    }
  }

#pragma unroll
  for (int m = 0; m < 4; ++m) {
    float4 st;
    st.x = acc[m][0]; st.y = acc[m][1]; st.z = acc[m][2]; st.w = acc[m][3];
    *reinterpret_cast<float4*>(&Gz[(size_t)(i0 + ty * 4 + m) * A_ + j0 + tx * 4]) = st;
  }
}

// ---------------------------------------------------------------------------
// Kernel 2: per-anchor 3-NN + Cayley-Menger det. (KPARTS=8 partial sums)
// ---------------------------------------------------------------------------
__device__ __forceinline__ void lexmin(float& v, int& j, float ov, int oj) {
  if (ov < v || (ov == v && oj < j)) { v = ov; j = oj; }
}

__global__ __launch_bounds__(64) void nn_det_kernel(
    const float* __restrict__ G, const float* __restrict__ sq,
    float* __restrict__ quality) {
  __shared__ float d2s[16];
  const int i = blockIdx.x;
  const int l = threadIdx.x;
  const float sqi = sq[i];
  const int jb = l * 8;

  float gg[8] = {0.f, 0.f, 0.f, 0.f, 0.f, 0.f, 0.f, 0.f};
#pragma unroll
  for (int z = 0; z < KPARTS; ++z) {
    const float* Grow = G + (size_t)z * A_ * A_ + (size_t)i * A_;
    float4 g0 = *reinterpret_cast<const float4*>(&Grow[jb]);
    float4 g1 = *reinterpret_cast<const float4*>(&Grow[jb + 4]);
    gg[0] += g0.x; gg[1] += g0.y; gg[2] += g0.z; gg[3] += g0.w;
    gg[4] += g1.x; gg[5] += g1.y; gg[6] += g1.z; gg[7] += g1.w;
  }
  float4 s0 = *reinterpret_cast<const float4*>(&sq[jb]);
  float4 s1 = *reinterpret_cast<const float4*>(&sq[jb + 4]);
  float ss[8] = { s0.x, s0.y, s0.z, s0.w, s1.x, s1.y, s1.z, s1.w };

  float dist[8];
#pragma unroll
  for (int q = 0; q < 8; ++q) {
    float d2 = fmaxf(sqi + ss[q] - 2.f * gg[q], 0.f);
    float dd = sqrtf(d2);
    if (jb + q == i) dd += 1e12f;
    dist[q] = dd;
  }

  int nn[NN_];
#pragma unroll
  for (int r = 0; r < NN_; ++r) {
    float bv = 1e30f;
    int bi = 0x7fffffff;
#pragma unroll
    for (int q = 0; q < 8; ++q) lexmin(bv, bi, dist[q], jb + q);
#pragma unroll
    for (int d = 1; d < 64; d <<= 1) {
      float ov = __shfl_xor(bv, d);
      int oi = __shfl_xor(bi, d);
      lexmin(bv, bi, ov, oi);
    }
    nn[r] = bi;
#pragma unroll
    for (int q = 0; q < 8; ++q)
      if (jb + q == bi) dist[q] = 1e30f;
  }

  if (l < 16) {
    const int p = l >> 2, q = l & 3;
    const int pi = (p == 0) ? i : ((p == 1) ? nn[0] : ((p == 2) ? nn[1] : nn[2]));
    const int qi = (q == 0) ? i : ((q == 1) ? nn[0] : ((q == 2) ? nn[1] : nn[2]));
    float d2f;
    if (p == q) {
      d2f = 0.f;
    } else {
      float g = 0.f;
#pragma unroll
      for (int z = 0; z < KPARTS; ++z)
        g += G[(size_t)z * A_ * A_ + (size_t)pi * A_ + qi];
      d2f = sq[pi] + sq[qi] - 2.f * g;
    }
    d2s[l] = d2f;
  }
  __syncthreads();

  if (l == 0) {
    double M[5][5];
    M[0][0] = 0.0;
    for (int q = 1; q < 5; ++q) { M[0][q] = 1.0; M[q][0] = 1.0; }
    for (int p = 0; p < 4; ++p)
      for (int q = 0; q < 4; ++q)
        M[p + 1][q + 1] = (double)d2s[p * 4 + q];

    double det = 1.0;
    for (int c = 0; c < 5; ++c) {
      int piv = c;
      double mx = fabs(M[c][c]);
      for (int r2 = c + 1; r2 < 5; ++r2) {
        double v = fabs(M[r2][c]);
        if (v > mx) { mx = v; piv = r2; }
      }
      if (piv != c) {
        for (int c2 = 0; c2 < 5; ++c2) { double tmp = M[c][c2]; M[c][c2] = M[piv][c2]; M[piv][c2] = tmp; }
        det = -det;
      }
      double pv = M[c][c];
      det *= pv;
      if (pv == 0.0) break;
      for (int r2 = c + 1; r2 < 5; ++r2) {
        double f = M[r2][c] / pv;
        for (int c2 = c; c2 < 5; ++c2) M[r2][c2] -= f * M[c][c2];
      }
    }
    float raw = (float)det;
    float sg = (raw > 0.f) ? 1.f : ((raw < 0.f) ? -1.f : 0.f);
    quality[i] = sg * logf(fabsf(raw) + 1e-12f);
  }
}

// ---------------------------------------------------------------------------
// Kernel 3: normalize quality. (unchanged)
// ---------------------------------------------------------------------------
__global__ __launch_bounds__(A_) void norm_cm_kernel(
    const float* __restrict__ quality, float* __restrict__ cmn) {
  __shared__ float red[A_];
  const int t = threadIdx.x;
  float q = quality[t];
  red[t] = q;
  __syncthreads();
  for (int s = A_ / 2; s > 0; s >>= 1) {
    if (t < s) red[t] += red[t + s];
    __syncthreads();
  }
  float mean = red[0] * (1.0f / A_);
  __syncthreads();
  float dq = q - mean;
  red[t] = dq * dq;
  __syncthreads();
  for (int s = A_ / 2; s > 0; s >>= 1) {
    if (t < s) red[t] += red[t + s];
    __syncthreads();
  }
  float sd = sqrtf(red[0] * (1.0f / (A_ - 1)));
  sd = fmaxf(sd, 1e-8f);
  cmn[t] = dq / sd;
}

// ---------------------------------------------------------------------------
// Kernel 4: FUSED rank + packed poly-MLP + sigmoid.
// Rank structure byte-identical to round 16; MLP now processes hidden units
// in pairs via float2 ext-vectors (v_pk_fma_f32 on gfx950).
// ---------------------------------------------------------------------------
__global__ __launch_bounds__(A_) void gate_fused(
    const float* __restrict__ tri, const float* __restrict__ cmn,
    const float* __restrict__ W1, const float* __restrict__ b1,
    const float* __restrict__ W2, const float* __restrict__ b2,
    float* __restrict__ out) {
  __shared__ int hist[256];
  __shared__ int pref[256];
  __shared__ int cursor[256];
  __shared__ unsigned long long sorted[A_];

  const int n = blockIdx.x;
  const int t = threadIdx.x;

  const float ti = tri[(size_t)n * A_ + t];
  const unsigned long long key =
      ((unsigned long long)__float_as_uint(ti) << 9) | (unsigned)t;
  int b = (int)(ti * 128.0f);
  b = (b < 0) ? 0 : ((b > 255) ? 255 : b);

  if (t < 256) { hist[t] = 0; cursor[t] = 0; }
  __syncthreads();
  atomicAdd(&hist[b], 1);
  __syncthreads();

  if (t < 64) {
    const int b4 = t * 4;
    int h0 = hist[b4 + 0], h1 = hist[b4 + 1], h2 = hist[b4 + 2], h3 = hist[b4 + 3];
    int s = h0 + h1 + h2 + h3;
    int incl = s;
#pragma unroll
    for (int d = 1; d < 64; d <<= 1) {
      int u = __shfl_up(incl, d);
      if (t >= d) incl += u;
    }
    int ex = incl - s;
    pref[b4 + 0] = ex;
    pref[b4 + 1] = ex + h0;
    pref[b4 + 2] = ex + h0 + h1;
    pref[b4 + 3] = ex + h0 + h1 + h2;
  }
  __syncthreads();

  const int pos = pref[b] + atomicAdd(&cursor[b], 1);
  sorted[pos] = key;
  __syncthreads();

  const int start = pref[b];
  const int len = hist[b];
  int cnt = start;
  for (int m = 0; m < len; ++m) cnt += (sorted[start + m] < key);
  const float rank = (float)cnt * (1.0f / (A_ - 1));

  const float f0 = cmn[t];
  const float f1 = 1.0f - ti;

  float logit = b2[0];
#pragma unroll
  for (int kp = 0; kp < 8; ++kp) {
    const int k0 = kp * 2, k1 = kp * 2 + 1;
    v2f w0; w0.x = W1[k0 * 3 + 0]; w0.y = W1[k1 * 3 + 0];
    v2f w1; w1.x = W1[k0 * 3 + 1]; w1.y = W1[k1 * 3 + 1];
    v2f w2; w2.x = W1[k0 * 3 + 2]; w2.y = W1[k1 * 3 + 2];
    v2f bb; bb.x = b1[k0];         bb.y = b1[k1];
    v2f x = w0 * f0 + (w1 * f1 + (w2 * rank + bb));
    v2f g = gelu_poly2(x);
    logit = fmaf(W2[k0], g.x, fmaf(W2[k1], g.y, logit));
  }
  const float eneg = exp2f(logit * -1.44269504088896340736f);
  out[(size_t)n * A_ + t] = __builtin_amdgcn_rcpf(1.0f + eneg);
}

// ---------------------------------------------------------------------------
extern "C" void kernel_launch(void* const* d_in, const int* in_sizes, int n_in,
                              void* d_out, int out_size, void* d_ws, size_t ws_size,
                              hipStream_t stream) {
  // inputs: 0 embedding (unused), 1 anchors, 2 tri, 3 W1, 4 b1, 5 W2, 6 b2
  const float* anchors = (const float*)d_in[1];
  const float* tri     = (const float*)d_in[2];
  const float* W1      = (const float*)d_in[3];
  const float* b1      = (const float*)d_in[4];
  const float* W2      = (const float*)d_in[5];
  const float* b2      = (const float*)d_in[6];
  float* out = (float*)d_out;

  float* G        = (float*)d_ws;                      // KPARTS*A_*A_ (8 MB)
  float* sq       = G + (size_t)KPARTS * A_ * A_;      // A_
  float* quality  = sq + A_;                           // A_
  float* cmn      = quality + A_;                      // A_

  sq_kernel<<<A_, 64, 0, stream>>>(anchors, sq);
  gram_tiled_kernel<<<dim3(8, 8, KPARTS), dim3(16, 16), 0, stream>>>(anchors, G);
  nn_det_kernel<<<A_, 64, 0, stream>>>(G, sq, quality);
  norm_cm_kernel<<<1, A_, 0, stream>>>(quality, cmn);
  gate_fused<<<N_, A_, 0, stream>>>(tri, cmn, W1, b1, W2, b2, out);
}